// Round 11
// baseline (7121.381 us; speedup 1.0000x reference)
//
#include <hip/hip_runtime.h>
#include <hip/hip_bf16.h>

// Problem dims (fixed)
#define B_ 64
#define T_ 512
#define D_ 1024
#define NQ_ (B_*T_*D_)      // 33554432
#define NI_ (B_*T_)         // 32768

typedef __attribute__((ext_vector_type(8))) short bf16x8;
typedef __attribute__((ext_vector_type(4))) float f32x4;

__device__ inline ushort f2bf(float f) {
    uint x = __float_as_uint(f);
    return (ushort)((x + 0x7FFFu + ((x >> 16) & 1u)) >> 16);
}
__device__ inline float bf2f(ushort u) { return __uint_as_float(((uint)u) << 16); }

__device__ __forceinline__ void astore64(ulong* p, ulong v) {
    __hip_atomic_store(p, v, __ATOMIC_RELAXED, __HIP_MEMORY_SCOPE_AGENT);
}

typedef const __attribute__((address_space(1))) void GV;
typedef __attribute__((address_space(3))) void LV;
__device__ __forceinline__ void gll16(const void* g, void* l) {
    __builtin_amdgcn_global_load_lds((GV*)g, (LV*)l, 16, 0, 0);
}

__device__ __forceinline__ float sigf(float x) { return 1.0f / (1.0f + __expf(-x)); }
__device__ __forceinline__ float tanhfast(float x) {
    float e = __expf(-2.0f * fabsf(x));
    float t = (1.0f - e) / (1.0f + e);
    return copysignf(t, x);
}

// ---------------- fp32 -> bf16 conversion ----------------
__global__ __launch_bounds__(256) void conv_kernel(const float* __restrict__ src,
                                                   ushort* __restrict__ dst, int n) {
    int i = (blockIdx.x * 256 + threadIdx.x) * 4;
    if (i >= n) return;
    float4 v = *reinterpret_cast<const float4*>(src + i);
    ushort4 o;
    o.x = f2bf(v.x); o.y = f2bf(v.y); o.z = f2bf(v.z); o.w = f2bf(v.w);
    *reinterpret_cast<ushort4*>(dst + i) = o;
}

// ---------------- Whh -> fragment-order pack: [jb64][g3][c32][lane64][8] ----------------
__global__ __launch_bounds__(256) void whhfr_kernel(const float* __restrict__ Whh,
                                                    ushort* __restrict__ Whh_fr) {
    int l = threadIdx.x & 63;
    int unit = blockIdx.x * 4 + (threadIdx.x >> 6);   // 0..6143 = jb*96 + g*32 + c
    int c = unit & 31;
    int g = (unit >> 5) % 3;
    int jb = unit / 96;
    int row = g * 1024 + jb * 16 + (l & 15);
    int k0 = c * 32 + (l >> 4) * 8;
    const float* s = Whh + (size_t)row * 1024 + k0;
    float4 f0 = *reinterpret_cast<const float4*>(s);
    float4 f1 = *reinterpret_cast<const float4*>(s + 4);
    uint4 pk;
    pk.x = (uint)f2bf(f0.x) | ((uint)f2bf(f0.y) << 16);
    pk.y = (uint)f2bf(f0.z) | ((uint)f2bf(f0.w) << 16);
    pk.z = (uint)f2bf(f1.x) | ((uint)f2bf(f1.y) << 16);
    pk.w = (uint)f2bf(f1.z) | ((uint)f2bf(f1.w) << 16);
    reinterpret_cast<uint4*>(Whh_fr)[(size_t)unit * 64 + l] = pk;
}

// ---- numpy-faithful fp32 pairwise sum of squares, n=1024 ----
__device__ inline float np_pairwise_sq_1024(const float* a) {
    float L[8];
    for (int c = 0; c < 8; ++c) {
        const float* p = a + c * 128;
        float r[8];
        #pragma unroll
        for (int k = 0; k < 8; ++k) r[k] = __fmul_rn(p[k], p[k]);
        for (int i = 8; i < 128; i += 8) {
            #pragma unroll
            for (int k = 0; k < 8; ++k) {
                float v = p[i + k];
                r[k] = __fadd_rn(r[k], __fmul_rn(v, v));
            }
        }
        L[c] = __fadd_rn(__fadd_rn(__fadd_rn(r[0], r[1]), __fadd_rn(r[2], r[3])),
                         __fadd_rn(__fadd_rn(r[4], r[5]), __fadd_rn(r[6], r[7])));
    }
    return __fadd_rn(__fadd_rn(__fadd_rn(L[0], L[1]), __fadd_rn(L[2], L[3])),
                     __fadd_rn(__fadd_rn(L[4], L[5]), __fadd_rn(L[6], L[7])));
}

__global__ __launch_bounds__(256) void c2_kernel(const float* __restrict__ cb,
                                                 float* __restrict__ c2) {
    int j = threadIdx.x;
    c2[j] = np_pairwise_sq_1024(cb + (size_t)j * D_);
}

// ---------------- quantize: fp32-faithful argmin ----------------
__global__ __launch_bounds__(256) void quantize_kernel(const float* __restrict__ Z,
                                                       const float* __restrict__ cb,
                                                       const float* __restrict__ c2,
                                                       float* __restrict__ qout,
                                                       float* __restrict__ idxout,
                                                       int* __restrict__ idxT) {
    __shared__ float rows[8][D_];
    __shared__ float z2s[8];
    __shared__ float d2s[256];
    __shared__ int   idxs[256];
    __shared__ int   bestIdx[8];
    int tid = threadIdx.x;
    size_t row0 = (size_t)blockIdx.x * 8;

    for (int p = 0; p < 8; ++p) {
        float4 v = *reinterpret_cast<const float4*>(Z + (row0 + p) * D_ + tid * 4);
        *reinterpret_cast<float4*>(&rows[p][tid * 4]) = v;
    }
    __syncthreads();

    if (tid < 8) z2s[tid] = np_pairwise_sq_1024(rows[tid]);

    float g2[8];
    #pragma unroll
    for (int r = 0; r < 8; ++r) g2[r] = 0.0f;
    const float* crow = cb + (size_t)tid * D_;
    for (int e = 0; e < D_; e += 4) {
        float4 cv = *reinterpret_cast<const float4*>(crow + e);
        #pragma unroll
        for (int r = 0; r < 8; ++r) {
            g2[r] = __fmaf_rn(__fmul_rn(2.0f, rows[r][e]),     cv.x, g2[r]);
            g2[r] = __fmaf_rn(__fmul_rn(2.0f, rows[r][e + 1]), cv.y, g2[r]);
            g2[r] = __fmaf_rn(__fmul_rn(2.0f, rows[r][e + 2]), cv.z, g2[r]);
            g2[r] = __fmaf_rn(__fmul_rn(2.0f, rows[r][e + 3]), cv.w, g2[r]);
        }
    }
    __syncthreads();

    for (int r = 0; r < 8; ++r) {
        d2s[tid] = __fadd_rn(__fsub_rn(z2s[r], g2[r]), c2[tid]);
        idxs[tid] = tid;
        __syncthreads();
        for (int s = 128; s > 0; s >>= 1) {
            if (tid < s) {
                float ov = d2s[tid + s]; int oi = idxs[tid + s];
                if (ov < d2s[tid] || (ov == d2s[tid] && oi < idxs[tid])) {
                    d2s[tid] = ov; idxs[tid] = oi;
                }
            }
            __syncthreads();
        }
        if (tid == 0) bestIdx[r] = idxs[0];
        __syncthreads();
    }

    if (tid < 8) {
        int row = (int)row0 + tid;
        idxout[row] = (float)bestIdx[tid];
        idxT[((row & 511) << 6) + (row >> 9)] = bestIdx[tid];
    }
    for (int r = 0; r < 8; ++r) {
        int bi = bestIdx[r];
        float4 v = *reinterpret_cast<const float4*>(cb + (size_t)bi * D_ + tid * 4);
        *reinterpret_cast<float4*>(qout + (row0 + r) * D_ + tid * 4) = v;
    }
}

// ---------------- Gp = bf16-packed (cb @ Wih^T + bih + bhh_{r,z}), [code][j][4] ----------------
__global__ __launch_bounds__(256) void gmat_kernel(const float* __restrict__ cb,
                                                   const float* __restrict__ Wih,
                                                   const float* __restrict__ bih,
                                                   const float* __restrict__ bhh,
                                                   ushort* __restrict__ Gp) {
    int m0 = blockIdx.x * 64;
    int n0 = blockIdx.y * 64;
    __shared__ ushort As[64][136];
    __shared__ ushort Bs[64][136];
    int tid = threadIdx.x;
    int w = tid >> 6, l = tid & 63, lr = l & 15, lk = l >> 4;
    f32x4 acc[4];
    #pragma unroll
    for (int i = 0; i < 4; ++i) acc[i] = f32x4{0.f, 0.f, 0.f, 0.f};

    for (int kc = 0; kc < D_; kc += 128) {
        for (int v = tid; v < 2048; v += 256) {
            int r = (v >> 4) & 63, kp = (v & 15) << 3;
            const float* src = (v < 1024) ? (cb  + (size_t)(m0 + r) * D_ + kc + kp)
                                          : (Wih + (size_t)(n0 + r) * D_ + kc + kp);
            float4 f0 = *reinterpret_cast<const float4*>(src);
            float4 f1 = *reinterpret_cast<const float4*>(src + 4);
            uint4 pk;
            pk.x = (uint)f2bf(f0.x) | ((uint)f2bf(f0.y) << 16);
            pk.y = (uint)f2bf(f0.z) | ((uint)f2bf(f0.w) << 16);
            pk.z = (uint)f2bf(f1.x) | ((uint)f2bf(f1.y) << 16);
            pk.w = (uint)f2bf(f1.z) | ((uint)f2bf(f1.w) << 16);
            ushort* dst = (v < 1024) ? &As[r][kp] : &Bs[r][kp];
            *reinterpret_cast<uint4*>(dst) = pk;
        }
        __syncthreads();
        #pragma unroll
        for (int kk = 0; kk < 4; ++kk) {
            bf16x8 bb = *reinterpret_cast<const bf16x8*>(&Bs[(w << 4) + lr][(kk << 5) + (lk << 3)]);
            #pragma unroll
            for (int mi = 0; mi < 4; ++mi) {
                bf16x8 a = *reinterpret_cast<const bf16x8*>(&As[(mi << 4) + lr][(kk << 5) + (lk << 3)]);
                acc[mi] = __builtin_amdgcn_mfma_f32_16x16x32_bf16(a, bb, acc[mi], 0, 0, 0);
            }
        }
        __syncthreads();
    }
    int n = n0 + (w << 4) + lr;
    int gate = n >> 10, jj = n & 1023;
    float bias = bih[n] + (gate < 2 ? bhh[n] : 0.0f);
    #pragma unroll
    for (int mi = 0; mi < 4; ++mi)
        #pragma unroll
        for (int reg = 0; reg < 4; ++reg) {
            int m = m0 + (mi << 4) + (lk << 2) + reg;
            Gp[((((size_t)m << 10) | jj) << 2) + gate] = f2bf(acc[mi][reg] + bias);
        }
}

// ---------------- persistent recurrence: wave-cohort flags, zero block barriers ----------------
// block = 16 j cols (A-operand Whh rows), wave w owns b rows 16w..16w+15 (closed cohort
// across blocks: wave w writes those rows' j-slice and stages exactly those rows)
__global__ __launch_bounds__(256, 1) void recur_kernel(
    const ushort* __restrict__ Whh_fr,
    const ushort* __restrict__ Gp,
    const int*    __restrict__ idxT,
    const float*  __restrict__ bhh,
    ushort* h_hist,      // [513][64][1024], slot 512 zeroed
    uint*   flags)       // 256 flags, 64B apart: [(blk<<2)+w] << 4
{
    extern __shared__ ushort dynlds[];          // [4 waves][32 chunks][64 lanes][8] = 128 KB
    const int tid = threadIdx.x, blk = blockIdx.x;
    const int w = tid >> 6, l = tid & 63;
    const int lr = l & 15, lk = l >> 4;
    const int j0 = blk << 4;
    const int b  = (w << 4) + lr;                    // this thread's batch row
    const int jq = j0 + (lk << 2);                   // first of 4 consecutive j
    const ushort* Bbase = Whh_fr + (size_t)blk * 49152;   // 3*32*64*8 per j-tile
    ushort* myfrag = dynlds + (w << 14);             // wave-private 32 KB
    const int rowoff = (b << 10) + (lk << 3);
    const float4 bhhn4 = *reinterpret_cast<const float4*>(&bhh[2048 + jq]);
    const float* bhhn = (const float*)&bhhn4;
    float hfp[4] = {0.f, 0.f, 0.f, 0.f};
    bool dead = false;
    uint* myflag   = &flags[((blk << 2) + w) << 4];
    uint* pollflag = &flags[((l << 2) + w) << 4];    // lane l <-> block l, cohort w

    for (int t = 0; t < T_; ++t) {
        // --- stage this wave's 16 h rows (full width) in fragment order ---
        const ushort* src = h_hist + ((size_t)(t == 0 ? 512 : t - 1) << 16) + rowoff;
        #pragma unroll
        for (int c = 0; c < 32; ++c)
            gll16(src + (c << 5), myfrag + (c << 9));

        // overlap: idx + 32B-contiguous Gp gather while staging is in flight
        const int ci = idxT[(t << 6) + b];
        const uint4* gpv = reinterpret_cast<const uint4*>(Gp + ((((size_t)ci << 10) | jq) << 2));
        uint4 ga = gpv[0], gb2 = gpv[1];
        ushort gp16[16];
        *reinterpret_cast<uint4*>(&gp16[0]) = ga;
        *reinterpret_cast<uint4*>(&gp16[8]) = gb2;

        // wave-local staging completion (LDS region is wave-private; no block barrier)
        asm volatile("s_waitcnt vmcnt(0)" ::: "memory");
        __builtin_amdgcn_sched_barrier(0);

        f32x4 acc0 = {0.f,0.f,0.f,0.f}, acc1 = acc0, acc2 = acc0;
        #pragma unroll 8
        for (int c = 0; c < 32; ++c) {
            bf16x8 hfr = *reinterpret_cast<const bf16x8*>(myfrag + (c << 9) + (l << 3));
            bf16x8 w0 = *reinterpret_cast<const bf16x8*>(Bbase +         (c << 9) + (l << 3));
            bf16x8 w1 = *reinterpret_cast<const bf16x8*>(Bbase + 16384 + (c << 9) + (l << 3));
            bf16x8 w2 = *reinterpret_cast<const bf16x8*>(Bbase + 32768 + (c << 9) + (l << 3));
            acc0 = __builtin_amdgcn_mfma_f32_16x16x32_bf16(w0, hfr, acc0, 0, 0, 0);  // D[j',b]
            acc1 = __builtin_amdgcn_mfma_f32_16x16x32_bf16(w1, hfr, acc1, 0, 0, 0);
            acc2 = __builtin_amdgcn_mfma_f32_16x16x32_bf16(w2, hfr, acc2, 0, 0, 0);
        }

        // gates for (b, j'=jq+reg); h store = one 8B agent store
        ushort4 hs;
        ushort* hsp = (ushort*)&hs;
        #pragma unroll
        for (int reg = 0; reg < 4; ++reg) {
            float rr = sigf(bf2f(gp16[reg * 4 + 0]) + acc0[reg]);
            float zz = sigf(bf2f(gp16[reg * 4 + 1]) + acc1[reg]);
            float nn = tanhfast(bf2f(gp16[reg * 4 + 2]) + rr * (acc2[reg] + bhhn[reg]));
            float hn = (1.0f - zz) * nn + zz * hfp[reg];
            hfp[reg] = hn;
            hsp[reg] = f2bf(hn);
        }
        astore64(reinterpret_cast<ulong*>(h_hist + ((size_t)t << 16) + (b << 10) + jq),
                 *reinterpret_cast<ulong*>(&hs));

        if (t < T_ - 1) {
            // per-wave release: drain own h stores, then publish cohort flag
            asm volatile("s_waitcnt vmcnt(0)" ::: "memory");
            __builtin_amdgcn_sched_barrier(0);
            if (l == 0)
                __hip_atomic_store(myflag, (uint)(t + 1),
                                   __ATOMIC_RELAXED, __HIP_MEMORY_SCOPE_AGENT);
            // per-lane spin: lane l waits for block l's cohort-w flag (1:1, fastest detect)
            if (!dead) {
                uint spins = 0;
                while (__hip_atomic_load(pollflag, __ATOMIC_RELAXED,
                                         __HIP_MEMORY_SCOPE_AGENT) < (uint)(t + 1)) {
                    if (++spins > (1u << 21)) { dead = true; break; }  // bounded: no hang
                }
            }
        }
    }
}

// ---------------- proj: hproj[t] = h_hist[t] @ projW^T + projb ----------------
__global__ __launch_bounds__(256) void proj_gemm_kernel(const ushort* __restrict__ h_hist,
                                                        const ushort* __restrict__ projW_bf,
                                                        const float* __restrict__ projb,
                                                        ushort* __restrict__ hproj,
                                                        int ch) {
    int t = ch * 256 + blockIdx.x;
    int n0 = blockIdx.y * 64;
    __shared__ ushort As[64][136];
    __shared__ ushort Bs[64][136];
    int tid = threadIdx.x;
    int w = tid >> 6, l = tid & 63, lr = l & 15, lk = l >> 4;
    f32x4 acc[4];
    #pragma unroll
    for (int i = 0; i < 4; ++i) acc[i] = f32x4{0.f,0.f,0.f,0.f};

    for (int kc = 0; kc < D_; kc += 128) {
        for (int v = tid; v < 2048; v += 256) {
            int r = (v >> 4) & 63, kp = (v & 15) << 3;
            if (v < 1024)
                *reinterpret_cast<uint4*>(&As[r][kp]) =
                    *reinterpret_cast<const uint4*>(h_hist + ((size_t)t << 16) + ((size_t)r << 10) + kc + kp);
            else
                *reinterpret_cast<uint4*>(&Bs[r][kp]) =
                    *reinterpret_cast<const uint4*>(projW_bf + ((size_t)(n0 + r) << 10) + kc + kp);
        }
        __syncthreads();
        #pragma unroll
        for (int kk = 0; kk < 4; ++kk) {
            bf16x8 bb = *reinterpret_cast<const bf16x8*>(&Bs[(w << 4) + lr][(kk << 5) + (lk << 3)]);
            #pragma unroll
            for (int mi = 0; mi < 4; ++mi) {
                bf16x8 a = *reinterpret_cast<const bf16x8*>(&As[(mi << 4) + lr][(kk << 5) + (lk << 3)]);
                acc[mi] = __builtin_amdgcn_mfma_f32_16x16x32_bf16(a, bb, acc[mi], 0, 0, 0);
            }
        }
        __syncthreads();
    }
    int n = n0 + (w << 4) + lr;
    float pb = projb[n];
    #pragma unroll
    for (int mi = 0; mi < 4; ++mi)
        #pragma unroll
        for (int reg = 0; reg < 4; ++reg) {
            int b = (mi << 4) + (lk << 2) + reg;
            hproj[((size_t)(t & 255) << 16) + (b << 10) + n] = f2bf(acc[mi][reg] + pb);
        }
}

// ---------------- CPC loss ----------------
__global__ __launch_bounds__(256) void cpc_loss_kernel(const ushort* __restrict__ hproj,
                                                       const float* __restrict__ Z,
                                                       double* __restrict__ cp_sum,
                                                       int ch) {
    int tp = ch * 256 + blockIdx.x;
    int k = blockIdx.y + 1;
    if (tp >= T_ - k) return;
    __shared__ float Hs[64][33];
    __shared__ float Zs[64][33];
    int tid = threadIdx.x;
    int tx = tid & 15, ty = tid >> 4;
    float acc[4][4] = {};
    const ushort* Hbase = hproj + ((size_t)(tp & 255) << 16);
    const float* Zbase = Z + (size_t)(tp + k) * D_;
    const size_t zstride = (size_t)T_ * D_;
    int r = tid >> 3, c = (tid & 7) << 2;

    for (int kc = 0; kc < D_; kc += 32) {
        #pragma unroll
        for (int p = 0; p < 2; ++p) {
            int rr2 = r + 32 * p;
            ushort4 hv = *reinterpret_cast<const ushort4*>(Hbase + (size_t)rr2 * D_ + kc + c);
            float4 zv = *reinterpret_cast<const float4*>(Zbase + (size_t)rr2 * zstride + kc + c);
            Hs[rr2][c] = bf2f(hv.x); Hs[rr2][c+1] = bf2f(hv.y);
            Hs[rr2][c+2] = bf2f(hv.z); Hs[rr2][c+3] = bf2f(hv.w);
            Zs[rr2][c] = zv.x; Zs[rr2][c+1] = zv.y; Zs[rr2][c+2] = zv.z; Zs[rr2][c+3] = zv.w;
        }
        __syncthreads();
        #pragma unroll
        for (int kk = 0; kk < 32; ++kk) {
            float av[4], bv[4];
            #pragma unroll
            for (int i = 0; i < 4; ++i) av[i] = Hs[ty + 16*i][kk];
            #pragma unroll
            for (int jv = 0; jv < 4; ++jv) bv[jv] = Zs[tx + 16*jv][kk];
            #pragma unroll
            for (int i = 0; i < 4; ++i)
                #pragma unroll
                for (int jv = 0; jv < 4; ++jv)
                    acc[i][jv] = __fmaf_rn(av[i], bv[jv], acc[i][jv]);
        }
        __syncthreads();
    }

    double lsum = 0.0;
    #pragma unroll
    for (int i = 0; i < 4; ++i) {
        #pragma unroll
        for (int jv = 0; jv < 4; ++jv) {
            int bb = ty + 16*i, cc2 = tx + 16*jv;
            double v = (double)acc[i][jv];
            double sg = 1.0 / (1.0 + exp(-v));
            lsum += (0.1 / 4096.0) * (-log(1.0 - sg + 1e-8));
            if (bb == cc2) lsum += (1.0 / 64.0) * (-log(sg + 1e-8));
        }
    }
    __shared__ double red[256];
    red[tid] = lsum; __syncthreads();
    for (int s2 = 128; s2 > 0; s2 >>= 1) {
        if (tid < s2) red[tid] += red[tid + s2];
        __syncthreads();
    }
    if (tid == 0) atomicAdd(cp_sum, red[0]);
}

// ---------------- VQ loss ----------------
__global__ __launch_bounds__(256) void vq_kernel(const float* __restrict__ Z,
                                                 const float* __restrict__ Q,
                                                 double* __restrict__ vq_sum) {
    size_t i0 = ((size_t)blockIdx.x * 256 + threadIdx.x) * 4;
    const size_t stride = (size_t)2048 * 256 * 4;
    double s = 0.0;
    for (size_t i = i0; i < (size_t)NQ_; i += stride) {
        float4 z = *reinterpret_cast<const float4*>(Z + i);
        float4 q = *reinterpret_cast<const float4*>(Q + i);
        double d0 = (double)z.x - (double)q.x;
        double d1 = (double)z.y - (double)q.y;
        double d2 = (double)z.z - (double)q.z;
        double d3 = (double)z.w - (double)q.w;
        s += d0*d0 + d1*d1 + d2*d2 + d3*d3;
    }
    __shared__ double red[256];
    int tid = threadIdx.x;
    red[tid] = s; __syncthreads();
    for (int k = 128; k > 0; k >>= 1) {
        if (tid < k) red[tid] += red[tid + k];
        __syncthreads();
    }
    if (tid == 0) atomicAdd(vq_sum, red[0]);
}

// ---------------- finalize ----------------
__global__ void finalize_kernel(const double* __restrict__ accum,
                                float* __restrict__ scal) {
    double cp = accum[0] / 1527.0;
    double vq = accum[1] * 1.25 / (double)NQ_;
    scal[0] = (float)(cp + vq);
    scal[1] = (float)cp;
    scal[2] = (float)vq;
}

extern "C" void kernel_launch(void* const* d_in, const int* in_sizes, int n_in,
                              void* d_out, int out_size, void* d_ws, size_t ws_size,
                              hipStream_t stream) {
    const float* Z     = (const float*)d_in[0];
    const float* cb    = (const float*)d_in[1];
    const float* Wih   = (const float*)d_in[2];
    const float* Whh   = (const float*)d_in[3];
    const float* bih   = (const float*)d_in[4];
    const float* bhh   = (const float*)d_in[5];
    const float* projW = (const float*)d_in[6];
    const float* projb = (const float*)d_in[7];

    float* out       = (float*)d_out;
    float* quantized = out;
    float* idxout    = out + (size_t)NQ_;
    float* scal      = out + (size_t)NQ_ + NI_;

    char* p = (char*)d_ws;
    ushort* Whh_fr   = (ushort*)p;  p += 6291456;
    ushort* projW_bf = (ushort*)p;  p += 2097152;
    ushort* Gp       = (ushort*)p;  p += 2097152;
    int*    idxT     = (int*)p;     p += 131072;
    float*  c2f      = (float*)p;   p += 4096;
    char*   ctrl     = p;           p += 20480;   // 16KB flags (256 x 64B) + accum
    ushort* h_hist   = (ushort*)p;  p += (size_t)513 * 131072;   // 67.24 MB
    ushort* hproj    = (ushort*)p;  p += (size_t)256 * 131072;   // 33.55 MB

    uint*   flags = (uint*)ctrl;
    double* accum = (double*)(ctrl + 16384);

    hipMemsetAsync(ctrl, 0, 20480, stream);
    hipMemsetAsync(h_hist + ((size_t)512 << 16), 0, 131072, stream);  // zero h0 slot

    conv_kernel<<<1024, 256, 0, stream>>>(projW, projW_bf, 1048576);
    whhfr_kernel<<<1536, 256, 0, stream>>>(Whh, Whh_fr);
    c2_kernel<<<1, 256, 0, stream>>>(cb, c2f);
    quantize_kernel<<<4096, 256, 0, stream>>>(Z, cb, c2f, quantized, idxout, idxT);
    gmat_kernel<<<dim3(4, 48), 256, 0, stream>>>(cb, Wih, bih, bhh, Gp);

    // 64 blocks x 256 threads, 128 KB dyn LDS -> 1 block/CU, co-resident on 64 of 256 CUs
    hipFuncSetAttribute(reinterpret_cast<const void*>(recur_kernel),
                        hipFuncAttributeMaxDynamicSharedMemorySize, 131072);
    recur_kernel<<<dim3(64), dim3(256), 131072, stream>>>(Whh_fr, Gp, idxT, bhh,
                                                          h_hist, flags);

    for (int ch = 0; ch < 2; ++ch) {
        proj_gemm_kernel<<<dim3(256, 16), 256, 0, stream>>>(h_hist, projW_bf, projb, hproj, ch);
        cpc_loss_kernel<<<dim3(256, 3), 256, 0, stream>>>(hproj, Z, &accum[0], ch);
    }

    vq_kernel<<<2048, 256, 0, stream>>>(Z, quantized, &accum[1]);
    finalize_kernel<<<1, 1, 0, stream>>>(accum, scal);
}

// Round 12
// 6400.806 us; speedup vs baseline: 1.1126x; 1.1126x over previous
//
#include <hip/hip_runtime.h>
#include <hip/hip_bf16.h>

// Problem dims (fixed)
#define B_ 64
#define T_ 512
#define D_ 1024
#define NQ_ (B_*T_*D_)      // 33554432
#define NI_ (B_*T_)         // 32768

typedef __attribute__((ext_vector_type(8))) short bf16x8;
typedef __attribute__((ext_vector_type(4))) float f32x4;

__device__ inline ushort f2bf(float f) {
    uint x = __float_as_uint(f);
    return (ushort)((x + 0x7FFFu + ((x >> 16) & 1u)) >> 16);
}
__device__ inline float bf2f(ushort u) { return __uint_as_float(((uint)u) << 16); }

__device__ __forceinline__ void astore64(ulong* p, ulong v) {
    __hip_atomic_store(p, v, __ATOMIC_RELAXED, __HIP_MEMORY_SCOPE_AGENT);
}

typedef const __attribute__((address_space(1))) void GV;
typedef __attribute__((address_space(3))) void LV;
__device__ __forceinline__ void gll16(const void* g, void* l) {
    __builtin_amdgcn_global_load_lds((GV*)g, (LV*)l, 16, 0, 0);
}

__device__ __forceinline__ float sigf(float x) { return 1.0f / (1.0f + __expf(-x)); }
__device__ __forceinline__ float tanhfast(float x) {
    float e = __expf(-2.0f * fabsf(x));
    float t = (1.0f - e) / (1.0f + e);
    return copysignf(t, x);
}

// ---------------- fp32 -> bf16 conversion ----------------
__global__ __launch_bounds__(256) void conv_kernel(const float* __restrict__ src,
                                                   ushort* __restrict__ dst, int n) {
    int i = (blockIdx.x * 256 + threadIdx.x) * 4;
    if (i >= n) return;
    float4 v = *reinterpret_cast<const float4*>(src + i);
    ushort4 o;
    o.x = f2bf(v.x); o.y = f2bf(v.y); o.z = f2bf(v.z); o.w = f2bf(v.w);
    *reinterpret_cast<ushort4*>(dst + i) = o;
}

// ---------------- Whh -> fragment-order pack: [jb64][g3][c32][lane64][8] ----------------
__global__ __launch_bounds__(256) void whhfr_kernel(const float* __restrict__ Whh,
                                                    ushort* __restrict__ Whh_fr) {
    int l = threadIdx.x & 63;
    int unit = blockIdx.x * 4 + (threadIdx.x >> 6);   // 0..6143 = jb*96 + g*32 + c
    int c = unit & 31;
    int g = (unit >> 5) % 3;
    int jb = unit / 96;
    int row = g * 1024 + jb * 16 + (l & 15);
    int k0 = c * 32 + (l >> 4) * 8;
    const float* s = Whh + (size_t)row * 1024 + k0;
    float4 f0 = *reinterpret_cast<const float4*>(s);
    float4 f1 = *reinterpret_cast<const float4*>(s + 4);
    uint4 pk;
    pk.x = (uint)f2bf(f0.x) | ((uint)f2bf(f0.y) << 16);
    pk.y = (uint)f2bf(f0.z) | ((uint)f2bf(f0.w) << 16);
    pk.z = (uint)f2bf(f1.x) | ((uint)f2bf(f1.y) << 16);
    pk.w = (uint)f2bf(f1.z) | ((uint)f2bf(f1.w) << 16);
    reinterpret_cast<uint4*>(Whh_fr)[(size_t)unit * 64 + l] = pk;
}

// ---- numpy-faithful fp32 pairwise sum of squares, n=1024 ----
__device__ inline float np_pairwise_sq_1024(const float* a) {
    float L[8];
    for (int c = 0; c < 8; ++c) {
        const float* p = a + c * 128;
        float r[8];
        #pragma unroll
        for (int k = 0; k < 8; ++k) r[k] = __fmul_rn(p[k], p[k]);
        for (int i = 8; i < 128; i += 8) {
            #pragma unroll
            for (int k = 0; k < 8; ++k) {
                float v = p[i + k];
                r[k] = __fadd_rn(r[k], __fmul_rn(v, v));
            }
        }
        L[c] = __fadd_rn(__fadd_rn(__fadd_rn(r[0], r[1]), __fadd_rn(r[2], r[3])),
                         __fadd_rn(__fadd_rn(r[4], r[5]), __fadd_rn(r[6], r[7])));
    }
    return __fadd_rn(__fadd_rn(__fadd_rn(L[0], L[1]), __fadd_rn(L[2], L[3])),
                     __fadd_rn(__fadd_rn(L[4], L[5]), __fadd_rn(L[6], L[7])));
}

__global__ __launch_bounds__(256) void c2_kernel(const float* __restrict__ cb,
                                                 float* __restrict__ c2) {
    int j = threadIdx.x;
    c2[j] = np_pairwise_sq_1024(cb + (size_t)j * D_);
}

// ---------------- quantize: fp32-faithful argmin + fused VQ loss ----------------
__global__ __launch_bounds__(256) void quantize_kernel(const float* __restrict__ Z,
                                                       const float* __restrict__ cb,
                                                       const float* __restrict__ c2,
                                                       float* __restrict__ qout,
                                                       float* __restrict__ idxout,
                                                       int* __restrict__ idxT,
                                                       double* __restrict__ vq_sum) {
    __shared__ float rows[8][D_];
    __shared__ float z2s[8];
    __shared__ float d2s[256];
    __shared__ int   idxs[256];
    __shared__ int   bestIdx[8];
    __shared__ double redv[256];
    int tid = threadIdx.x;
    size_t row0 = (size_t)blockIdx.x * 8;

    for (int p = 0; p < 8; ++p) {
        float4 v = *reinterpret_cast<const float4*>(Z + (row0 + p) * D_ + tid * 4);
        *reinterpret_cast<float4*>(&rows[p][tid * 4]) = v;
    }
    __syncthreads();

    if (tid < 8) z2s[tid] = np_pairwise_sq_1024(rows[tid]);

    float g2[8];
    #pragma unroll
    for (int r = 0; r < 8; ++r) g2[r] = 0.0f;
    const float* crow = cb + (size_t)tid * D_;
    for (int e = 0; e < D_; e += 4) {
        float4 cv = *reinterpret_cast<const float4*>(crow + e);
        #pragma unroll
        for (int r = 0; r < 8; ++r) {
            g2[r] = __fmaf_rn(__fmul_rn(2.0f, rows[r][e]),     cv.x, g2[r]);
            g2[r] = __fmaf_rn(__fmul_rn(2.0f, rows[r][e + 1]), cv.y, g2[r]);
            g2[r] = __fmaf_rn(__fmul_rn(2.0f, rows[r][e + 2]), cv.z, g2[r]);
            g2[r] = __fmaf_rn(__fmul_rn(2.0f, rows[r][e + 3]), cv.w, g2[r]);
        }
    }
    __syncthreads();

    for (int r = 0; r < 8; ++r) {
        d2s[tid] = __fadd_rn(__fsub_rn(z2s[r], g2[r]), c2[tid]);
        idxs[tid] = tid;
        __syncthreads();
        for (int s = 128; s > 0; s >>= 1) {
            if (tid < s) {
                float ov = d2s[tid + s]; int oi = idxs[tid + s];
                if (ov < d2s[tid] || (ov == d2s[tid] && oi < idxs[tid])) {
                    d2s[tid] = ov; idxs[tid] = oi;
                }
            }
            __syncthreads();
        }
        if (tid == 0) bestIdx[r] = idxs[0];
        __syncthreads();
    }

    if (tid < 8) {
        int row = (int)row0 + tid;
        idxout[row] = (float)bestIdx[tid];
        idxT[((row & 511) << 6) + (row >> 9)] = bestIdx[tid];
    }

    // qout write + fused VQ partial: (z - q)^2 over this block's 8 rows
    double vqp = 0.0;
    for (int r = 0; r < 8; ++r) {
        int bi = bestIdx[r];
        float4 v = *reinterpret_cast<const float4*>(cb + (size_t)bi * D_ + tid * 4);
        *reinterpret_cast<float4*>(qout + (row0 + r) * D_ + tid * 4) = v;
        const float* zr = &rows[r][tid * 4];
        double d0 = (double)zr[0] - (double)v.x;
        double d1 = (double)zr[1] - (double)v.y;
        double d2 = (double)zr[2] - (double)v.z;
        double d3 = (double)zr[3] - (double)v.w;
        vqp += d0*d0 + d1*d1 + d2*d2 + d3*d3;
    }
    redv[tid] = vqp; __syncthreads();
    for (int s = 128; s > 0; s >>= 1) {
        if (tid < s) redv[tid] += redv[tid + s];
        __syncthreads();
    }
    if (tid == 0) atomicAdd(vq_sum, redv[0]);
}

// ---------------- Gp = bf16-packed (cb @ Wih^T + bih + bhh_{r,z}), [code][j][4] ----------------
__global__ __launch_bounds__(256) void gmat_kernel(const float* __restrict__ cb,
                                                   const float* __restrict__ Wih,
                                                   const float* __restrict__ bih,
                                                   const float* __restrict__ bhh,
                                                   ushort* __restrict__ Gp) {
    int m0 = blockIdx.x * 64;
    int n0 = blockIdx.y * 64;
    __shared__ ushort As[64][136];
    __shared__ ushort Bs[64][136];
    int tid = threadIdx.x;
    int w = tid >> 6, l = tid & 63, lr = l & 15, lk = l >> 4;
    f32x4 acc[4];
    #pragma unroll
    for (int i = 0; i < 4; ++i) acc[i] = f32x4{0.f, 0.f, 0.f, 0.f};

    for (int kc = 0; kc < D_; kc += 128) {
        for (int v = tid; v < 2048; v += 256) {
            int r = (v >> 4) & 63, kp = (v & 15) << 3;
            const float* src = (v < 1024) ? (cb  + (size_t)(m0 + r) * D_ + kc + kp)
                                          : (Wih + (size_t)(n0 + r) * D_ + kc + kp);
            float4 f0 = *reinterpret_cast<const float4*>(src);
            float4 f1 = *reinterpret_cast<const float4*>(src + 4);
            uint4 pk;
            pk.x = (uint)f2bf(f0.x) | ((uint)f2bf(f0.y) << 16);
            pk.y = (uint)f2bf(f0.z) | ((uint)f2bf(f0.w) << 16);
            pk.z = (uint)f2bf(f1.x) | ((uint)f2bf(f1.y) << 16);
            pk.w = (uint)f2bf(f1.z) | ((uint)f2bf(f1.w) << 16);
            ushort* dst = (v < 1024) ? &As[r][kp] : &Bs[r][kp];
            *reinterpret_cast<uint4*>(dst) = pk;
        }
        __syncthreads();
        #pragma unroll
        for (int kk = 0; kk < 4; ++kk) {
            bf16x8 bb = *reinterpret_cast<const bf16x8*>(&Bs[(w << 4) + lr][(kk << 5) + (lk << 3)]);
            #pragma unroll
            for (int mi = 0; mi < 4; ++mi) {
                bf16x8 a = *reinterpret_cast<const bf16x8*>(&As[(mi << 4) + lr][(kk << 5) + (lk << 3)]);
                acc[mi] = __builtin_amdgcn_mfma_f32_16x16x32_bf16(a, bb, acc[mi], 0, 0, 0);
            }
        }
        __syncthreads();
    }
    int n = n0 + (w << 4) + lr;
    int gate = n >> 10, jj = n & 1023;
    float bias = bih[n] + (gate < 2 ? bhh[n] : 0.0f);
    #pragma unroll
    for (int mi = 0; mi < 4; ++mi)
        #pragma unroll
        for (int reg = 0; reg < 4; ++reg) {
            int m = m0 + (mi << 4) + (lk << 2) + reg;
            Gp[((((size_t)m << 10) | jj) << 2) + gate] = f2bf(acc[mi][reg] + bias);
        }
}

// ---------------- persistent recurrence: R8 barrier/poll + contiguous stores ----------------
// block = 16 j cols (A-operand Whh rows), wave w = b rows 16w..16w+15 (B-operand h rows)
// thread epilogue owns (b = 16w + lr, j' = j0 + 4*lk + reg) -> one 8B agent store
__global__ __launch_bounds__(256, 1) void recur_kernel(
    const ushort* __restrict__ Whh_fr,
    const ushort* __restrict__ Gp,
    const int*    __restrict__ idxT,
    const float*  __restrict__ bhh,
    ushort* h_hist,      // [513][64][1024], slot 512 zeroed
    uint*   flags)       // 64 flags, 64B apart
{
    extern __shared__ ushort dynlds[];          // [4 waves][32 chunks][64 lanes][8] = 128 KB
    const int tid = threadIdx.x, blk = blockIdx.x;
    const int w = tid >> 6, l = tid & 63;
    const int lr = l & 15, lk = l >> 4;
    const int j0 = blk << 4;
    const int b  = (w << 4) + lr;                    // this thread's batch row
    const int jq = j0 + (lk << 2);                   // first of 4 consecutive j
    const ushort* Bbase = Whh_fr + (size_t)blk * 49152;   // 3*32*64*8 per j-tile
    ushort* myfrag = dynlds + (w << 14);             // wave-private 32 KB
    const int rowoff = (b << 10) + (lk << 3);
    const float4 bhhn4 = *reinterpret_cast<const float4*>(&bhh[2048 + jq]);
    const float* bhhn = (const float*)&bhhn4;
    float hfp[4] = {0.f, 0.f, 0.f, 0.f};
    bool dead = false;

    for (int t = 0; t < T_; ++t) {
        // --- stage this wave's 16 h rows (full width) in fragment order ---
        const ushort* src = h_hist + ((size_t)(t == 0 ? 512 : t - 1) << 16) + rowoff;
        #pragma unroll
        for (int c = 0; c < 32; ++c)
            gll16(src + (c << 5), myfrag + (c << 9));

        // overlap: idx + 32B-contiguous Gp gather while staging is in flight
        const int ci = idxT[(t << 6) + b];
        const uint4* gpv = reinterpret_cast<const uint4*>(Gp + ((((size_t)ci << 10) | jq) << 2));
        uint4 ga = gpv[0], gb2 = gpv[1];
        ushort gp16[16];
        *reinterpret_cast<uint4*>(&gp16[0]) = ga;
        *reinterpret_cast<uint4*>(&gp16[8]) = gb2;

        // wave-local staging completion (LDS region is wave-private)
        asm volatile("s_waitcnt vmcnt(0)" ::: "memory");
        __builtin_amdgcn_sched_barrier(0);

        f32x4 acc0 = {0.f,0.f,0.f,0.f}, acc1 = acc0, acc2 = acc0;
        #pragma unroll
        for (int c = 0; c < 32; ++c) {
            bf16x8 hfr = *reinterpret_cast<const bf16x8*>(myfrag + (c << 9) + (l << 3));
            bf16x8 w0 = *reinterpret_cast<const bf16x8*>(Bbase +         (c << 9) + (l << 3));
            bf16x8 w1 = *reinterpret_cast<const bf16x8*>(Bbase + 16384 + (c << 9) + (l << 3));
            bf16x8 w2 = *reinterpret_cast<const bf16x8*>(Bbase + 32768 + (c << 9) + (l << 3));
            acc0 = __builtin_amdgcn_mfma_f32_16x16x32_bf16(w0, hfr, acc0, 0, 0, 0);  // D[j',b]
            acc1 = __builtin_amdgcn_mfma_f32_16x16x32_bf16(w1, hfr, acc1, 0, 0, 0);
            acc2 = __builtin_amdgcn_mfma_f32_16x16x32_bf16(w2, hfr, acc2, 0, 0, 0);
        }

        // gates for (b, j'=jq+reg); h store = one 8B agent store
        ushort4 hs;
        ushort* hsp = (ushort*)&hs;
        #pragma unroll
        for (int reg = 0; reg < 4; ++reg) {
            float rr = sigf(bf2f(gp16[reg * 4 + 0]) + acc0[reg]);
            float zz = sigf(bf2f(gp16[reg * 4 + 1]) + acc1[reg]);
            float nn = tanhfast(bf2f(gp16[reg * 4 + 2]) + rr * (acc2[reg] + bhhn[reg]));
            float hn = (1.0f - zz) * nn + zz * hfp[reg];
            hfp[reg] = hn;
            hsp[reg] = f2bf(hn);
        }
        astore64(reinterpret_cast<ulong*>(h_hist + ((size_t)t << 16) + (b << 10) + jq),
                 *reinterpret_cast<ulong*>(&hs));

        if (t < T_ - 1) {
            __syncthreads();   // drains vmcnt(0) before s_barrier -> all waves' h stores landed
            if (tid == 0)
                __hip_atomic_store(&flags[blk << 4], (uint)(t + 1),
                                   __ATOMIC_RELAXED, __HIP_MEMORY_SCOPE_AGENT);
            if (!dead) {       // all 256 threads spin, each on one of 64 flag lines (R8 pattern)
                uint spins = 0;
                while (__hip_atomic_load(&flags[(tid & 63) << 4], __ATOMIC_RELAXED,
                                         __HIP_MEMORY_SCOPE_AGENT) < (uint)(t + 1)) {
                    if (++spins > (1u << 20)) { dead = true; break; }  // bounded: no hang
                }
            }
            __syncthreads();
        }
    }
}

// ---------------- proj: hproj[t] = h_hist[t] @ projW^T + projb ----------------
__global__ __launch_bounds__(256) void proj_gemm_kernel(const ushort* __restrict__ h_hist,
                                                        const ushort* __restrict__ projW_bf,
                                                        const float* __restrict__ projb,
                                                        ushort* __restrict__ hproj,
                                                        int ch) {
    int t = ch * 256 + blockIdx.x;
    int n0 = blockIdx.y * 64;
    __shared__ ushort As[64][136];
    __shared__ ushort Bs[64][136];
    int tid = threadIdx.x;
    int w = tid >> 6, l = tid & 63, lr = l & 15, lk = l >> 4;
    f32x4 acc[4];
    #pragma unroll
    for (int i = 0; i < 4; ++i) acc[i] = f32x4{0.f,0.f,0.f,0.f};

    for (int kc = 0; kc < D_; kc += 128) {
        for (int v = tid; v < 2048; v += 256) {
            int r = (v >> 4) & 63, kp = (v & 15) << 3;
            if (v < 1024)
                *reinterpret_cast<uint4*>(&As[r][kp]) =
                    *reinterpret_cast<const uint4*>(h_hist + ((size_t)t << 16) + ((size_t)r << 10) + kc + kp);
            else
                *reinterpret_cast<uint4*>(&Bs[r][kp]) =
                    *reinterpret_cast<const uint4*>(projW_bf + ((size_t)(n0 + r) << 10) + kc + kp);
        }
        __syncthreads();
        #pragma unroll
        for (int kk = 0; kk < 4; ++kk) {
            bf16x8 bb = *reinterpret_cast<const bf16x8*>(&Bs[(w << 4) + lr][(kk << 5) + (lk << 3)]);
            #pragma unroll
            for (int mi = 0; mi < 4; ++mi) {
                bf16x8 a = *reinterpret_cast<const bf16x8*>(&As[(mi << 4) + lr][(kk << 5) + (lk << 3)]);
                acc[mi] = __builtin_amdgcn_mfma_f32_16x16x32_bf16(a, bb, acc[mi], 0, 0, 0);
            }
        }
        __syncthreads();
    }
    int n = n0 + (w << 4) + lr;
    float pb = projb[n];
    #pragma unroll
    for (int mi = 0; mi < 4; ++mi)
        #pragma unroll
        for (int reg = 0; reg < 4; ++reg) {
            int b = (mi << 4) + (lk << 2) + reg;
            hproj[((size_t)(t & 255) << 16) + (b << 10) + n] = f2bf(acc[mi][reg] + pb);
        }
}

// ---------------- CPC loss ----------------
__global__ __launch_bounds__(256) void cpc_loss_kernel(const ushort* __restrict__ hproj,
                                                       const float* __restrict__ Z,
                                                       double* __restrict__ cp_sum,
                                                       int ch) {
    int tp = ch * 256 + blockIdx.x;
    int k = blockIdx.y + 1;
    if (tp >= T_ - k) return;
    __shared__ float Hs[64][33];
    __shared__ float Zs[64][33];
    int tid = threadIdx.x;
    int tx = tid & 15, ty = tid >> 4;
    float acc[4][4] = {};
    const ushort* Hbase = hproj + ((size_t)(tp & 255) << 16);
    const float* Zbase = Z + (size_t)(tp + k) * D_;
    const size_t zstride = (size_t)T_ * D_;
    int r = tid >> 3, c = (tid & 7) << 2;

    for (int kc = 0; kc < D_; kc += 32) {
        #pragma unroll
        for (int p = 0; p < 2; ++p) {
            int rr2 = r + 32 * p;
            ushort4 hv = *reinterpret_cast<const ushort4*>(Hbase + (size_t)rr2 * D_ + kc + c);
            float4 zv = *reinterpret_cast<const float4*>(Zbase + (size_t)rr2 * zstride + kc + c);
            Hs[rr2][c] = bf2f(hv.x); Hs[rr2][c+1] = bf2f(hv.y);
            Hs[rr2][c+2] = bf2f(hv.z); Hs[rr2][c+3] = bf2f(hv.w);
            Zs[rr2][c] = zv.x; Zs[rr2][c+1] = zv.y; Zs[rr2][c+2] = zv.z; Zs[rr2][c+3] = zv.w;
        }
        __syncthreads();
        #pragma unroll
        for (int kk = 0; kk < 32; ++kk) {
            float av[4], bv[4];
            #pragma unroll
            for (int i = 0; i < 4; ++i) av[i] = Hs[ty + 16*i][kk];
            #pragma unroll
            for (int jv = 0; jv < 4; ++jv) bv[jv] = Zs[tx + 16*jv][kk];
            #pragma unroll
            for (int i = 0; i < 4; ++i)
                #pragma unroll
                for (int jv = 0; jv < 4; ++jv)
                    acc[i][jv] = __fmaf_rn(av[i], bv[jv], acc[i][jv]);
        }
        __syncthreads();
    }

    double lsum = 0.0;
    #pragma unroll
    for (int i = 0; i < 4; ++i) {
        #pragma unroll
        for (int jv = 0; jv < 4; ++jv) {
            int bb = ty + 16*i, cc2 = tx + 16*jv;
            double v = (double)acc[i][jv];
            double sg = 1.0 / (1.0 + exp(-v));
            lsum += (0.1 / 4096.0) * (-log(1.0 - sg + 1e-8));
            if (bb == cc2) lsum += (1.0 / 64.0) * (-log(sg + 1e-8));
        }
    }
    __shared__ double red[256];
    red[tid] = lsum; __syncthreads();
    for (int s2 = 128; s2 > 0; s2 >>= 1) {
        if (tid < s2) red[tid] += red[tid + s2];
        __syncthreads();
    }
    if (tid == 0) atomicAdd(cp_sum, red[0]);
}

// ---------------- finalize ----------------
__global__ void finalize_kernel(const double* __restrict__ accum,
                                float* __restrict__ scal) {
    double cp = accum[0] / 1527.0;
    double vq = accum[1] * 1.25 / (double)NQ_;
    scal[0] = (float)(cp + vq);
    scal[1] = (float)cp;
    scal[2] = (float)vq;
}

extern "C" void kernel_launch(void* const* d_in, const int* in_sizes, int n_in,
                              void* d_out, int out_size, void* d_ws, size_t ws_size,
                              hipStream_t stream) {
    const float* Z     = (const float*)d_in[0];
    const float* cb    = (const float*)d_in[1];
    const float* Wih   = (const float*)d_in[2];
    const float* Whh   = (const float*)d_in[3];
    const float* bih   = (const float*)d_in[4];
    const float* bhh   = (const float*)d_in[5];
    const float* projW = (const float*)d_in[6];
    const float* projb = (const float*)d_in[7];

    float* out       = (float*)d_out;
    float* quantized = out;
    float* idxout    = out + (size_t)NQ_;
    float* scal      = out + (size_t)NQ_ + NI_;

    char* p = (char*)d_ws;
    ushort* Whh_fr   = (ushort*)p;  p += 6291456;
    ushort* projW_bf = (ushort*)p;  p += 2097152;
    ushort* Gp       = (ushort*)p;  p += 2097152;
    int*    idxT     = (int*)p;     p += 131072;
    float*  c2f      = (float*)p;   p += 4096;
    char*   ctrl     = p;           p += 8192;    // 4KB flags (64 x 64B) + accum
    ushort* h_hist   = (ushort*)p;  p += (size_t)513 * 131072;   // 67.24 MB
    ushort* hproj    = (ushort*)p;  p += (size_t)256 * 131072;   // 33.55 MB

    uint*   flags = (uint*)ctrl;
    double* accum = (double*)(ctrl + 4096);

    hipMemsetAsync(ctrl, 0, 8192, stream);
    hipMemsetAsync(h_hist + ((size_t)512 << 16), 0, 131072, stream);  // zero h0 slot

    conv_kernel<<<1024, 256, 0, stream>>>(projW, projW_bf, 1048576);
    whhfr_kernel<<<1536, 256, 0, stream>>>(Whh, Whh_fr);
    c2_kernel<<<1, 256, 0, stream>>>(cb, c2f);
    quantize_kernel<<<4096, 256, 0, stream>>>(Z, cb, c2f, quantized, idxout, idxT,
                                              &accum[1]);
    gmat_kernel<<<dim3(4, 48), 256, 0, stream>>>(cb, Wih, bih, bhh, Gp);

    // 64 blocks x 256 threads, 128 KB dyn LDS -> 1 block/CU, co-resident on 64 of 256 CUs
    hipFuncSetAttribute(reinterpret_cast<const void*>(recur_kernel),
                        hipFuncAttributeMaxDynamicSharedMemorySize, 131072);
    recur_kernel<<<dim3(64), dim3(256), 131072, stream>>>(Whh_fr, Gp, idxT, bhh,
                                                          h_hist, flags);

    for (int ch = 0; ch < 2; ++ch) {
        proj_gemm_kernel<<<dim3(256, 16), 256, 0, stream>>>(h_hist, projW_bf, projb, hproj, ch);
        cpc_loss_kernel<<<dim3(256, 3), 256, 0, stream>>>(hproj, Z, &accum[0], ch);
    }

    finalize_kernel<<<1, 1, 0, stream>>>(accum, scal);
}

// Round 14
// 5911.633 us; speedup vs baseline: 1.2046x; 1.0827x over previous
//
#include <hip/hip_runtime.h>
#include <hip/hip_bf16.h>

// Problem dims (fixed)
#define B_ 64
#define T_ 512
#define D_ 1024
#define NQ_ (B_*T_*D_)      // 33554432
#define NI_ (B_*T_)         // 32768

typedef __attribute__((ext_vector_type(8))) short bf16x8;
typedef __attribute__((ext_vector_type(4))) float f32x4;

__device__ inline ushort f2bf(float f) {
    uint x = __float_as_uint(f);
    return (ushort)((x + 0x7FFFu + ((x >> 16) & 1u)) >> 16);
}
__device__ inline float bf2f(ushort u) { return __uint_as_float(((uint)u) << 16); }

__device__ __forceinline__ void astore(ushort* p, ushort v) {
    __hip_atomic_store(p, v, __ATOMIC_RELAXED, __HIP_MEMORY_SCOPE_AGENT);
}

typedef const __attribute__((address_space(1))) void GV;
typedef __attribute__((address_space(3))) void LV;
__device__ __forceinline__ void gll16(const void* g, void* l) {
    __builtin_amdgcn_global_load_lds((GV*)g, (LV*)l, 16, 0, 0);
}

__device__ __forceinline__ float sigf(float x) { return 1.0f / (1.0f + __expf(-x)); }
__device__ __forceinline__ float tanhfast(float x) {
    float e = __expf(-2.0f * fabsf(x));
    float t = (1.0f - e) / (1.0f + e);
    return copysignf(t, x);
}

// ---------------- fp32 -> bf16 conversion ----------------
__global__ __launch_bounds__(256) void conv_kernel(const float* __restrict__ src,
                                                   ushort* __restrict__ dst, int n) {
    int i = (blockIdx.x * 256 + threadIdx.x) * 4;
    if (i >= n) return;
    float4 v = *reinterpret_cast<const float4*>(src + i);
    ushort4 o;
    o.x = f2bf(v.x); o.y = f2bf(v.y); o.z = f2bf(v.z); o.w = f2bf(v.w);
    *reinterpret_cast<ushort4*>(dst + i) = o;
}

// ---------------- Whh -> fragment-order pack: [jb64][g3][c32][lane64][8] ----------------
__global__ __launch_bounds__(256) void whhfr_kernel(const float* __restrict__ Whh,
                                                    ushort* __restrict__ Whh_fr) {
    int l = threadIdx.x & 63;
    int unit = blockIdx.x * 4 + (threadIdx.x >> 6);   // 0..6143 = jb*96 + g*32 + c
    int c = unit & 31;
    int g = (unit >> 5) % 3;
    int jb = unit / 96;
    int row = g * 1024 + jb * 16 + (l & 15);
    int k0 = c * 32 + (l >> 4) * 8;
    const float* s = Whh + (size_t)row * 1024 + k0;
    float4 f0 = *reinterpret_cast<const float4*>(s);
    float4 f1 = *reinterpret_cast<const float4*>(s + 4);
    uint4 pk;
    pk.x = (uint)f2bf(f0.x) | ((uint)f2bf(f0.y) << 16);
    pk.y = (uint)f2bf(f0.z) | ((uint)f2bf(f0.w) << 16);
    pk.z = (uint)f2bf(f1.x) | ((uint)f2bf(f1.y) << 16);
    pk.w = (uint)f2bf(f1.z) | ((uint)f2bf(f1.w) << 16);
    reinterpret_cast<uint4*>(Whh_fr)[(size_t)unit * 64 + l] = pk;
}

// ---- numpy-faithful fp32 pairwise sum of squares, n=1024 ----
__device__ inline float np_pairwise_sq_1024(const float* a) {
    float L[8];
    for (int c = 0; c < 8; ++c) {
        const float* p = a + c * 128;
        float r[8];
        #pragma unroll
        for (int k = 0; k < 8; ++k) r[k] = __fmul_rn(p[k], p[k]);
        for (int i = 8; i < 128; i += 8) {
            #pragma unroll
            for (int k = 0; k < 8; ++k) {
                float v = p[i + k];
                r[k] = __fadd_rn(r[k], __fmul_rn(v, v));
            }
        }
        L[c] = __fadd_rn(__fadd_rn(__fadd_rn(r[0], r[1]), __fadd_rn(r[2], r[3])),
                         __fadd_rn(__fadd_rn(r[4], r[5]), __fadd_rn(r[6], r[7])));
    }
    return __fadd_rn(__fadd_rn(__fadd_rn(L[0], L[1]), __fadd_rn(L[2], L[3])),
                     __fadd_rn(__fadd_rn(L[4], L[5]), __fadd_rn(L[6], L[7])));
}

__global__ __launch_bounds__(256) void c2_kernel(const float* __restrict__ cb,
                                                 float* __restrict__ c2) {
    int j = threadIdx.x;
    c2[j] = np_pairwise_sq_1024(cb + (size_t)j * D_);
}

// ---------------- quantize: fp32-faithful argmin + fused VQ loss ----------------
__global__ __launch_bounds__(256) void quantize_kernel(const float* __restrict__ Z,
                                                       const float* __restrict__ cb,
                                                       const float* __restrict__ c2,
                                                       float* __restrict__ qout,
                                                       float* __restrict__ idxout,
                                                       int* __restrict__ idxT,
                                                       double* __restrict__ vq_sum) {
    __shared__ float rows[8][D_];
    __shared__ float z2s[8];
    __shared__ float d2s[256];
    __shared__ int   idxs[256];
    __shared__ int   bestIdx[8];
    __shared__ double redv[256];
    int tid = threadIdx.x;
    size_t row0 = (size_t)blockIdx.x * 8;

    for (int p = 0; p < 8; ++p) {
        float4 v = *reinterpret_cast<const float4*>(Z + (row0 + p) * D_ + tid * 4);
        *reinterpret_cast<float4*>(&rows[p][tid * 4]) = v;
    }
    __syncthreads();

    if (tid < 8) z2s[tid] = np_pairwise_sq_1024(rows[tid]);

    float g2[8];
    #pragma unroll
    for (int r = 0; r < 8; ++r) g2[r] = 0.0f;
    const float* crow = cb + (size_t)tid * D_;
    for (int e = 0; e < D_; e += 4) {
        float4 cv = *reinterpret_cast<const float4*>(crow + e);
        #pragma unroll
        for (int r = 0; r < 8; ++r) {
            g2[r] = __fmaf_rn(__fmul_rn(2.0f, rows[r][e]),     cv.x, g2[r]);
            g2[r] = __fmaf_rn(__fmul_rn(2.0f, rows[r][e + 1]), cv.y, g2[r]);
            g2[r] = __fmaf_rn(__fmul_rn(2.0f, rows[r][e + 2]), cv.z, g2[r]);
            g2[r] = __fmaf_rn(__fmul_rn(2.0f, rows[r][e + 3]), cv.w, g2[r]);
        }
    }
    __syncthreads();

    for (int r = 0; r < 8; ++r) {
        d2s[tid] = __fadd_rn(__fsub_rn(z2s[r], g2[r]), c2[tid]);
        idxs[tid] = tid;
        __syncthreads();
        for (int s = 128; s > 0; s >>= 1) {
            if (tid < s) {
                float ov = d2s[tid + s]; int oi = idxs[tid + s];
                if (ov < d2s[tid] || (ov == d2s[tid] && oi < idxs[tid])) {
                    d2s[tid] = ov; idxs[tid] = oi;
                }
            }
            __syncthreads();
        }
        if (tid == 0) bestIdx[r] = idxs[0];
        __syncthreads();
    }

    if (tid < 8) {
        int row = (int)row0 + tid;
        idxout[row] = (float)bestIdx[tid];
        idxT[((row & 511) << 6) + (row >> 9)] = bestIdx[tid];
    }

    // qout write + fused VQ partial: (z - q)^2 over this block's 8 rows
    double vqp = 0.0;
    for (int r = 0; r < 8; ++r) {
        int bi = bestIdx[r];
        float4 v = *reinterpret_cast<const float4*>(cb + (size_t)bi * D_ + tid * 4);
        *reinterpret_cast<float4*>(qout + (row0 + r) * D_ + tid * 4) = v;
        const float* zr = &rows[r][tid * 4];
        double d0 = (double)zr[0] - (double)v.x;
        double d1 = (double)zr[1] - (double)v.y;
        double d2 = (double)zr[2] - (double)v.z;
        double d3 = (double)zr[3] - (double)v.w;
        vqp += d0*d0 + d1*d1 + d2*d2 + d3*d3;
    }
    redv[tid] = vqp; __syncthreads();
    for (int s = 128; s > 0; s >>= 1) {
        if (tid < s) redv[tid] += redv[tid + s];
        __syncthreads();
    }
    if (tid == 0) atomicAdd(vq_sum, redv[0]);
}

// ---------------- Gp = bf16-packed (cb @ Wih^T + bih + bhh_{r,z}), [code][j][4] ----------------
__global__ __launch_bounds__(256) void gmat_kernel(const float* __restrict__ cb,
                                                   const float* __restrict__ Wih,
                                                   const float* __restrict__ bih,
                                                   const float* __restrict__ bhh,
                                                   ushort* __restrict__ Gp) {
    int m0 = blockIdx.x * 64;
    int n0 = blockIdx.y * 64;
    __shared__ ushort As[64][136];
    __shared__ ushort Bs[64][136];
    int tid = threadIdx.x;
    int w = tid >> 6, l = tid & 63, lr = l & 15, lk = l >> 4;
    f32x4 acc[4];
    #pragma unroll
    for (int i = 0; i < 4; ++i) acc[i] = f32x4{0.f, 0.f, 0.f, 0.f};

    for (int kc = 0; kc < D_; kc += 128) {
        for (int v = tid; v < 2048; v += 256) {
            int r = (v >> 4) & 63, kp = (v & 15) << 3;
            const float* src = (v < 1024) ? (cb  + (size_t)(m0 + r) * D_ + kc + kp)
                                          : (Wih + (size_t)(n0 + r) * D_ + kc + kp);
            float4 f0 = *reinterpret_cast<const float4*>(src);
            float4 f1 = *reinterpret_cast<const float4*>(src + 4);
            uint4 pk;
            pk.x = (uint)f2bf(f0.x) | ((uint)f2bf(f0.y) << 16);
            pk.y = (uint)f2bf(f0.z) | ((uint)f2bf(f0.w) << 16);
            pk.z = (uint)f2bf(f1.x) | ((uint)f2bf(f1.y) << 16);
            pk.w = (uint)f2bf(f1.z) | ((uint)f2bf(f1.w) << 16);
            ushort* dst = (v < 1024) ? &As[r][kp] : &Bs[r][kp];
            *reinterpret_cast<uint4*>(dst) = pk;
        }
        __syncthreads();
        #pragma unroll
        for (int kk = 0; kk < 4; ++kk) {
            bf16x8 bb = *reinterpret_cast<const bf16x8*>(&Bs[(w << 4) + lr][(kk << 5) + (lk << 3)]);
            #pragma unroll
            for (int mi = 0; mi < 4; ++mi) {
                bf16x8 a = *reinterpret_cast<const bf16x8*>(&As[(mi << 4) + lr][(kk << 5) + (lk << 3)]);
                acc[mi] = __builtin_amdgcn_mfma_f32_16x16x32_bf16(a, bb, acc[mi], 0, 0, 0);
            }
        }
        __syncthreads();
    }
    int n = n0 + (w << 4) + lr;
    int gate = n >> 10, jj = n & 1023;
    float bias = bih[n] + (gate < 2 ? bhh[n] : 0.0f);
    #pragma unroll
    for (int mi = 0; mi < 4; ++mi)
        #pragma unroll
        for (int reg = 0; reg < 4; ++reg) {
            int m = m0 + (mi << 4) + (lk << 2) + reg;
            Gp[((((size_t)m << 10) | jj) << 2) + gate] = f2bf(acc[mi][reg] + bias);
        }
}

// ---------------- persistent recurrence: R8-verbatim (best measured, 4.25 ms) ----------------
__global__ __launch_bounds__(256, 1) void recur_kernel(
    const ushort* __restrict__ Whh_fr,
    const ushort* __restrict__ Gp,
    const int*    __restrict__ idxT,
    const float*  __restrict__ bhh,
    ushort* h_hist,      // [513][64][1024], slot 512 zeroed
    uint*   flags)
{
    extern __shared__ ushort dynlds[];          // [4][32][64][8] = 128 KB
    const int tid = threadIdx.x, blk = blockIdx.x;
    const int w = tid >> 6, l = tid & 63;
    const int lr = l & 15, lk = l >> 4;
    const int j0 = blk << 4, j = j0 + lr;
    const int b_base = (w << 4) + (lk << 2);
    const float bhhn = bhh[2048 + j];
    const ushort* Bbase = Whh_fr + (size_t)blk * 49152;   // 3*32*64*8
    ushort* myfrag = dynlds + (w << 14);                  // w*32*512
    const int rowoff = (((w << 4) + lr) << 10) + (lk << 3);
    float hfp[4] = {0.f, 0.f, 0.f, 0.f};
    bool dead = false;

    for (int t = 0; t < T_; ++t) {
        const ushort* src = h_hist + ((size_t)(t == 0 ? 512 : t - 1) << 16) + rowoff;
        #pragma unroll
        for (int c = 0; c < 32; ++c)
            gll16(src + (c << 5), myfrag + (c << 9));
        __syncthreads();   // drains gll vmcnt

        f32x4 acc0 = {0.f,0.f,0.f,0.f}, acc1 = acc0, acc2 = acc0;
        #pragma unroll
        for (int c = 0; c < 32; ++c) {
            bf16x8 a = *reinterpret_cast<const bf16x8*>(myfrag + (c << 9) + (l << 3));
            bf16x8 b0 = *reinterpret_cast<const bf16x8*>(Bbase +         (c << 9) + (l << 3));
            bf16x8 b1 = *reinterpret_cast<const bf16x8*>(Bbase + 16384 + (c << 9) + (l << 3));
            bf16x8 b2 = *reinterpret_cast<const bf16x8*>(Bbase + 32768 + (c << 9) + (l << 3));
            acc0 = __builtin_amdgcn_mfma_f32_16x16x32_bf16(a, b0, acc0, 0, 0, 0);
            acc1 = __builtin_amdgcn_mfma_f32_16x16x32_bf16(a, b1, acc1, 0, 0, 0);
            acc2 = __builtin_amdgcn_mfma_f32_16x16x32_bf16(a, b2, acc2, 0, 0, 0);
        }

        ushort* hw = h_hist + ((size_t)t << 16);
        const uint4 it4 = *reinterpret_cast<const uint4*>(idxT + (t << 6) + b_base);
        const int* itp = (const int*)&it4;
        #pragma unroll
        for (int reg = 0; reg < 4; ++reg) {
            const int b = b_base + reg;
            const ushort4 g4 = *reinterpret_cast<const ushort4*>(Gp + ((((size_t)itp[reg] << 10) | j) << 2));
            float rr = sigf(bf2f(g4.x) + acc0[reg]);
            float zz = sigf(bf2f(g4.y) + acc1[reg]);
            float nn = tanhfast(bf2f(g4.z) + rr * (acc2[reg] + bhhn));
            float hn = (1.0f - zz) * nn + zz * hfp[reg];
            hfp[reg] = hn;
            astore(&hw[(b << 10) + j], f2bf(hn));
        }

        if (t < T_ - 1) {
            __syncthreads();   // compiler emits vmcnt(0) drain before s_barrier -> h stores landed
            if (tid == 0)
                __hip_atomic_store(&flags[blk << 4], (uint)(t + 1),
                                   __ATOMIC_RELAXED, __HIP_MEMORY_SCOPE_AGENT);
            if (!dead) {       // all 256 threads busy-poll (fast detect + keeps clocks up)
                uint spins = 0;
                while (__hip_atomic_load(&flags[(tid & 63) << 4], __ATOMIC_RELAXED,
                                         __HIP_MEMORY_SCOPE_AGENT) < (uint)(t + 1)) {
                    if (++spins > (1u << 20)) { dead = true; break; }  // bounded: no hang
                }
            }
            __syncthreads();
        }
    }
}

// ---------------- proj: hproj[t] = h_hist[t] @ projW^T + projb ----------------
__global__ __launch_bounds__(256) void proj_gemm_kernel(const ushort* __restrict__ h_hist,
                                                        const ushort* __restrict__ projW_bf,
                                                        const float* __restrict__ projb,
                                                        ushort* __restrict__ hproj,
                                                        int ch) {
    int t = ch * 256 + blockIdx.x;
    int n0 = blockIdx.y * 64;
    __shared__ ushort As[64][136];
    __shared__ ushort Bs[64][136];
    int tid = threadIdx.x;
    int w = tid >> 6, l = tid & 63, lr = l & 15, lk = l >> 4;
    f32x4 acc[4];
    #pragma unroll
    for (int i = 0; i < 4; ++i) acc[i] = f32x4{0.f,0.f,0.f,0.f};

    for (int kc = 0; kc < D_; kc += 128) {
        for (int v = tid; v < 2048; v += 256) {
            int r = (v >> 4) & 63, kp = (v & 15) << 3;
            if (v < 1024)
                *reinterpret_cast<uint4*>(&As[r][kp]) =
                    *reinterpret_cast<const uint4*>(h_hist + ((size_t)t << 16) + ((size_t)r << 10) + kc + kp);
            else
                *reinterpret_cast<uint4*>(&Bs[r][kp]) =
                    *reinterpret_cast<const uint4*>(projW_bf + ((size_t)(n0 + r) << 10) + kc + kp);
        }
        __syncthreads();
        #pragma unroll
        for (int kk = 0; kk < 4; ++kk) {
            bf16x8 bb = *reinterpret_cast<const bf16x8*>(&Bs[(w << 4) + lr][(kk << 5) + (lk << 3)]);
            #pragma unroll
            for (int mi = 0; mi < 4; ++mi) {
                bf16x8 a = *reinterpret_cast<const bf16x8*>(&As[(mi << 4) + lr][(kk << 5) + (lk << 3)]);
                acc[mi] = __builtin_amdgcn_mfma_f32_16x16x32_bf16(a, bb, acc[mi], 0, 0, 0);
            }
        }
        __syncthreads();
    }
    int n = n0 + (w << 4) + lr;
    float pb = projb[n];
    #pragma unroll
    for (int mi = 0; mi < 4; ++mi)
        #pragma unroll
        for (int reg = 0; reg < 4; ++reg) {
            int b = (mi << 4) + (lk << 2) + reg;
            hproj[((size_t)(t & 255) << 16) + (b << 10) + n] = f2bf(acc[mi][reg] + pb);
        }
}

// ---------------- CPC loss ----------------
__global__ __launch_bounds__(256) void cpc_loss_kernel(const ushort* __restrict__ hproj,
                                                       const float* __restrict__ Z,
                                                       double* __restrict__ cp_sum,
                                                       int ch) {
    int tp = ch * 256 + blockIdx.x;
    int k = blockIdx.y + 1;
    if (tp >= T_ - k) return;
    __shared__ float Hs[64][33];
    __shared__ float Zs[64][33];
    int tid = threadIdx.x;
    int tx = tid & 15, ty = tid >> 4;
    float acc[4][4] = {};
    const ushort* Hbase = hproj + ((size_t)(tp & 255) << 16);
    const float* Zbase = Z + (size_t)(tp + k) * D_;
    const size_t zstride = (size_t)T_ * D_;
    int r = tid >> 3, c = (tid & 7) << 2;

    for (int kc = 0; kc < D_; kc += 32) {
        #pragma unroll
        for (int p = 0; p < 2; ++p) {
            int rr2 = r + 32 * p;
            ushort4 hv = *reinterpret_cast<const ushort4*>(Hbase + (size_t)rr2 * D_ + kc + c);
            float4 zv = *reinterpret_cast<const float4*>(Zbase + (size_t)rr2 * zstride + kc + c);
            Hs[rr2][c] = bf2f(hv.x); Hs[rr2][c+1] = bf2f(hv.y);
            Hs[rr2][c+2] = bf2f(hv.z); Hs[rr2][c+3] = bf2f(hv.w);
            Zs[rr2][c] = zv.x; Zs[rr2][c+1] = zv.y; Zs[rr2][c+2] = zv.z; Zs[rr2][c+3] = zv.w;
        }
        __syncthreads();
        #pragma unroll
        for (int kk = 0; kk < 32; ++kk) {
            float av[4], bv[4];
            #pragma unroll
            for (int i = 0; i < 4; ++i) av[i] = Hs[ty + 16*i][kk];
            #pragma unroll
            for (int jv = 0; jv < 4; ++jv) bv[jv] = Zs[tx + 16*jv][kk];
            #pragma unroll
            for (int i = 0; i < 4; ++i)
                #pragma unroll
                for (int jv = 0; jv < 4; ++jv)
                    acc[i][jv] = __fmaf_rn(av[i], bv[jv], acc[i][jv]);
        }
        __syncthreads();
    }

    double lsum = 0.0;
    #pragma unroll
    for (int i = 0; i < 4; ++i) {
        #pragma unroll
        for (int jv = 0; jv < 4; ++jv) {
            int bb = ty + 16*i, cc2 = tx + 16*jv;
            double v = (double)acc[i][jv];
            double sg = 1.0 / (1.0 + exp(-v));
            lsum += (0.1 / 4096.0) * (-log(1.0 - sg + 1e-8));
            if (bb == cc2) lsum += (1.0 / 64.0) * (-log(sg + 1e-8));
        }
    }
    __shared__ double red[256];
    red[tid] = lsum; __syncthreads();
    for (int s2 = 128; s2 > 0; s2 >>= 1) {
        if (tid < s2) red[tid] += red[tid + s2];
        __syncthreads();
    }
    if (tid == 0) atomicAdd(cp_sum, red[0]);
}

// ---------------- finalize ----------------
__global__ void finalize_kernel(const double* __restrict__ accum,
                                float* __restrict__ scal) {
    double cp = accum[0] / 1527.0;
    double vq = accum[1] * 1.25 / (double)NQ_;
    scal[0] = (float)(cp + vq);
    scal[1] = (float)cp;
    scal[2] = (float)vq;
}

extern "C" void kernel_launch(void* const* d_in, const int* in_sizes, int n_in,
                              void* d_out, int out_size, void* d_ws, size_t ws_size,
                              hipStream_t stream) {
    const float* Z     = (const float*)d_in[0];
    const float* cb    = (const float*)d_in[1];
    const float* Wih   = (const float*)d_in[2];
    const float* Whh   = (const float*)d_in[3];
    const float* bih   = (const float*)d_in[4];
    const float* bhh   = (const float*)d_in[5];
    const float* projW = (const float*)d_in[6];
    const float* projb = (const float*)d_in[7];

    float* out       = (float*)d_out;
    float* quantized = out;
    float* idxout    = out + (size_t)NQ_;
    float* scal      = out + (size_t)NQ_ + NI_;

    char* p = (char*)d_ws;
    ushort* Whh_fr   = (ushort*)p;  p += 6291456;
    ushort* projW_bf = (ushort*)p;  p += 2097152;
    ushort* Gp       = (ushort*)p;  p += 2097152;
    int*    idxT     = (int*)p;     p += 131072;
    float*  c2f      = (float*)p;   p += 4096;
    char*   ctrl     = p;           p += 8192;    // 4KB flags (64 x 64B) + accum
    ushort* h_hist   = (ushort*)p;  p += (size_t)513 * 131072;   // 67.24 MB
    ushort* hproj    = (ushort*)p;  p += (size_t)256 * 131072;   // 33.55 MB

    uint*   flags = (uint*)ctrl;
    double* accum = (double*)(ctrl + 4096);

    hipMemsetAsync(ctrl, 0, 8192, stream);
    hipMemsetAsync(h_hist + ((size_t)512 << 16), 0, 131072, stream);  // zero h0 slot

    conv_kernel<<<1024, 256, 0, stream>>>(projW, projW_bf, 1048576);
    whhfr_kernel<<<1536, 256, 0, stream>>>(Whh, Whh_fr);
    c2_kernel<<<1, 256, 0, stream>>>(cb, c2f);
    quantize_kernel<<<4096, 256, 0, stream>>>(Z, cb, c2f, quantized, idxout, idxT,
                                              &accum[1]);
    gmat_kernel<<<dim3(4, 48), 256, 0, stream>>>(cb, Wih, bih, bhh, Gp);

    // 64 blocks x 256 threads, 128 KB dyn LDS -> 1 block/CU, co-resident on 64 of 256 CUs
    hipFuncSetAttribute(reinterpret_cast<const void*>(recur_kernel),
                        hipFuncAttributeMaxDynamicSharedMemorySize, 131072);
    recur_kernel<<<dim3(64), dim3(256), 131072, stream>>>(Whh_fr, Gp, idxT, bhh,
                                                          h_hist, flags);

    for (int ch = 0; ch < 2; ++ch) {
        proj_gemm_kernel<<<dim3(256, 16), 256, 0, stream>>>(h_hist, projW_bf, projb, hproj, ch);
        cpc_loss_kernel<<<dim3(256, 3), 256, 0, stream>>>(hproj, Z, &accum[0], ch);
    }

    finalize_kernel<<<1, 1, 0, stream>>>(accum, scal);
}

// Round 15
// 5562.555 us; speedup vs baseline: 1.2802x; 1.0628x over previous
//
#include <hip/hip_runtime.h>
#include <hip/hip_bf16.h>

// Problem dims (fixed)
#define B_ 64
#define T_ 512
#define D_ 1024
#define NQ_ (B_*T_*D_)      // 33554432
#define NI_ (B_*T_)         // 32768

typedef __attribute__((ext_vector_type(8))) short bf16x8;
typedef __attribute__((ext_vector_type(4))) float f32x4;

__device__ inline ushort f2bf(float f) {
    uint x = __float_as_uint(f);
    return (ushort)((x + 0x7FFFu + ((x >> 16) & 1u)) >> 16);
}
__device__ inline float bf2f(ushort u) { return __uint_as_float(((uint)u) << 16); }

__device__ __forceinline__ void astore(ushort* p, ushort v) {
    __hip_atomic_store(p, v, __ATOMIC_RELAXED, __HIP_MEMORY_SCOPE_AGENT);
}

typedef const __attribute__((address_space(1))) void GV;
typedef __attribute__((address_space(3))) void LV;
__device__ __forceinline__ void gll16(const void* g, void* l) {
    __builtin_amdgcn_global_load_lds((GV*)g, (LV*)l, 16, 0, 0);
}

__device__ __forceinline__ float sigf(float x) { return 1.0f / (1.0f + __expf(-x)); }
__device__ __forceinline__ float tanhfast(float x) {
    float e = __expf(-2.0f * fabsf(x));
    float t = (1.0f - e) / (1.0f + e);
    return copysignf(t, x);
}

// ---------------- Whh -> fragment-order pack: [jb64][g3][c32][lane64][8] ----------------
__global__ __launch_bounds__(256) void whhfr_kernel(const float* __restrict__ Whh,
                                                    ushort* __restrict__ Whh_fr) {
    int l = threadIdx.x & 63;
    int unit = blockIdx.x * 4 + (threadIdx.x >> 6);   // 0..6143 = jb*96 + g*32 + c
    int c = unit & 31;
    int g = (unit >> 5) % 3;
    int jb = unit / 96;
    int row = g * 1024 + jb * 16 + (l & 15);
    int k0 = c * 32 + (l >> 4) * 8;
    const float* s = Whh + (size_t)row * 1024 + k0;
    float4 f0 = *reinterpret_cast<const float4*>(s);
    float4 f1 = *reinterpret_cast<const float4*>(s + 4);
    uint4 pk;
    pk.x = (uint)f2bf(f0.x) | ((uint)f2bf(f0.y) << 16);
    pk.y = (uint)f2bf(f0.z) | ((uint)f2bf(f0.w) << 16);
    pk.z = (uint)f2bf(f1.x) | ((uint)f2bf(f1.y) << 16);
    pk.w = (uint)f2bf(f1.z) | ((uint)f2bf(f1.w) << 16);
    reinterpret_cast<uint4*>(Whh_fr)[(size_t)unit * 64 + l] = pk;
}

// ---------------- projW -> fragment-order pack: [ng64][c32][lane64][8] ----------------
__global__ __launch_bounds__(256) void pwfr_kernel(const float* __restrict__ projW,
                                                   ushort* __restrict__ pW_fr) {
    int l = threadIdx.x & 63;
    int unit = blockIdx.x * 4 + (threadIdx.x >> 6);   // 0..2047 = ng*32 + c
    int c = unit & 31;
    int ng = unit >> 5;
    int row = ng * 16 + (l & 15);
    int k0 = c * 32 + (l >> 4) * 8;
    const float* s = projW + (size_t)row * 1024 + k0;
    float4 f0 = *reinterpret_cast<const float4*>(s);
    float4 f1 = *reinterpret_cast<const float4*>(s + 4);
    uint4 pk;
    pk.x = (uint)f2bf(f0.x) | ((uint)f2bf(f0.y) << 16);
    pk.y = (uint)f2bf(f0.z) | ((uint)f2bf(f0.w) << 16);
    pk.z = (uint)f2bf(f1.x) | ((uint)f2bf(f1.y) << 16);
    pk.w = (uint)f2bf(f1.z) | ((uint)f2bf(f1.w) << 16);
    reinterpret_cast<uint4*>(pW_fr)[(size_t)unit * 64 + l] = pk;
}

// ---- numpy-faithful fp32 pairwise sum of squares, n=1024 ----
__device__ inline float np_pairwise_sq_1024(const float* a) {
    float L[8];
    for (int c = 0; c < 8; ++c) {
        const float* p = a + c * 128;
        float r[8];
        #pragma unroll
        for (int k = 0; k < 8; ++k) r[k] = __fmul_rn(p[k], p[k]);
        for (int i = 8; i < 128; i += 8) {
            #pragma unroll
            for (int k = 0; k < 8; ++k) {
                float v = p[i + k];
                r[k] = __fadd_rn(r[k], __fmul_rn(v, v));
            }
        }
        L[c] = __fadd_rn(__fadd_rn(__fadd_rn(r[0], r[1]), __fadd_rn(r[2], r[3])),
                         __fadd_rn(__fadd_rn(r[4], r[5]), __fadd_rn(r[6], r[7])));
    }
    return __fadd_rn(__fadd_rn(__fadd_rn(L[0], L[1]), __fadd_rn(L[2], L[3])),
                     __fadd_rn(__fadd_rn(L[4], L[5]), __fadd_rn(L[6], L[7])));
}

__global__ __launch_bounds__(256) void c2_kernel(const float* __restrict__ cb,
                                                 float* __restrict__ c2) {
    int j = threadIdx.x;
    c2[j] = np_pairwise_sq_1024(cb + (size_t)j * D_);
}

// ---------------- quantize: fp32-faithful argmin + fused VQ loss ----------------
__global__ __launch_bounds__(256) void quantize_kernel(const float* __restrict__ Z,
                                                       const float* __restrict__ cb,
                                                       const float* __restrict__ c2,
                                                       float* __restrict__ qout,
                                                       float* __restrict__ idxout,
                                                       int* __restrict__ idxT,
                                                       double* __restrict__ vq_sum) {
    __shared__ float rows[8][D_];
    __shared__ float z2s[8];
    __shared__ float d2s[256];
    __shared__ int   idxs[256];
    __shared__ int   bestIdx[8];
    __shared__ double redv[256];
    int tid = threadIdx.x;
    size_t row0 = (size_t)blockIdx.x * 8;

    for (int p = 0; p < 8; ++p) {
        float4 v = *reinterpret_cast<const float4*>(Z + (row0 + p) * D_ + tid * 4);
        *reinterpret_cast<float4*>(&rows[p][tid * 4]) = v;
    }
    __syncthreads();

    if (tid < 8) z2s[tid] = np_pairwise_sq_1024(rows[tid]);

    float g2[8];
    #pragma unroll
    for (int r = 0; r < 8; ++r) g2[r] = 0.0f;
    const float* crow = cb + (size_t)tid * D_;
    for (int e = 0; e < D_; e += 4) {
        float4 cv = *reinterpret_cast<const float4*>(crow + e);
        #pragma unroll
        for (int r = 0; r < 8; ++r) {
            g2[r] = __fmaf_rn(__fmul_rn(2.0f, rows[r][e]),     cv.x, g2[r]);
            g2[r] = __fmaf_rn(__fmul_rn(2.0f, rows[r][e + 1]), cv.y, g2[r]);
            g2[r] = __fmaf_rn(__fmul_rn(2.0f, rows[r][e + 2]), cv.z, g2[r]);
            g2[r] = __fmaf_rn(__fmul_rn(2.0f, rows[r][e + 3]), cv.w, g2[r]);
        }
    }
    __syncthreads();

    for (int r = 0; r < 8; ++r) {
        d2s[tid] = __fadd_rn(__fsub_rn(z2s[r], g2[r]), c2[tid]);
        idxs[tid] = tid;
        __syncthreads();
        for (int s = 128; s > 0; s >>= 1) {
            if (tid < s) {
                float ov = d2s[tid + s]; int oi = idxs[tid + s];
                if (ov < d2s[tid] || (ov == d2s[tid] && oi < idxs[tid])) {
                    d2s[tid] = ov; idxs[tid] = oi;
                }
            }
            __syncthreads();
        }
        if (tid == 0) bestIdx[r] = idxs[0];
        __syncthreads();
    }

    if (tid < 8) {
        int row = (int)row0 + tid;
        idxout[row] = (float)bestIdx[tid];
        idxT[((row & 511) << 6) + (row >> 9)] = bestIdx[tid];
    }

    double vqp = 0.0;
    for (int r = 0; r < 8; ++r) {
        int bi = bestIdx[r];
        float4 v = *reinterpret_cast<const float4*>(cb + (size_t)bi * D_ + tid * 4);
        *reinterpret_cast<float4*>(qout + (row0 + r) * D_ + tid * 4) = v;
        const float* zr = &rows[r][tid * 4];
        double d0 = (double)zr[0] - (double)v.x;
        double d1 = (double)zr[1] - (double)v.y;
        double d2 = (double)zr[2] - (double)v.z;
        double d3 = (double)zr[3] - (double)v.w;
        vqp += d0*d0 + d1*d1 + d2*d2 + d3*d3;
    }
    redv[tid] = vqp; __syncthreads();
    for (int s = 128; s > 0; s >>= 1) {
        if (tid < s) redv[tid] += redv[tid + s];
        __syncthreads();
    }
    if (tid == 0) atomicAdd(vq_sum, redv[0]);
}

// ---------------- Gp = bf16-packed (cb @ Wih^T + bih + bhh_{r,z}), [code][j][4] ----------------
__global__ __launch_bounds__(256) void gmat_kernel(const float* __restrict__ cb,
                                                   const float* __restrict__ Wih,
                                                   const float* __restrict__ bih,
                                                   const float* __restrict__ bhh,
                                                   ushort* __restrict__ Gp) {
    int m0 = blockIdx.x * 64;
    int n0 = blockIdx.y * 64;
    __shared__ ushort As[64][136];
    __shared__ ushort Bs[64][136];
    int tid = threadIdx.x;
    int w = tid >> 6, l = tid & 63, lr = l & 15, lk = l >> 4;
    f32x4 acc[4];
    #pragma unroll
    for (int i = 0; i < 4; ++i) acc[i] = f32x4{0.f, 0.f, 0.f, 0.f};

    for (int kc = 0; kc < D_; kc += 128) {
        for (int v = tid; v < 2048; v += 256) {
            int r = (v >> 4) & 63, kp = (v & 15) << 3;
            const float* src = (v < 1024) ? (cb  + (size_t)(m0 + r) * D_ + kc + kp)
                                          : (Wih + (size_t)(n0 + r) * D_ + kc + kp);
            float4 f0 = *reinterpret_cast<const float4*>(src);
            float4 f1 = *reinterpret_cast<const float4*>(src + 4);
            uint4 pk;
            pk.x = (uint)f2bf(f0.x) | ((uint)f2bf(f0.y) << 16);
            pk.y = (uint)f2bf(f0.z) | ((uint)f2bf(f0.w) << 16);
            pk.z = (uint)f2bf(f1.x) | ((uint)f2bf(f1.y) << 16);
            pk.w = (uint)f2bf(f1.z) | ((uint)f2bf(f1.w) << 16);
            ushort* dst = (v < 1024) ? &As[r][kp] : &Bs[r][kp];
            *reinterpret_cast<uint4*>(dst) = pk;
        }
        __syncthreads();
        #pragma unroll
        for (int kk = 0; kk < 4; ++kk) {
            bf16x8 bb = *reinterpret_cast<const bf16x8*>(&Bs[(w << 4) + lr][(kk << 5) + (lk << 3)]);
            #pragma unroll
            for (int mi = 0; mi < 4; ++mi) {
                bf16x8 a = *reinterpret_cast<const bf16x8*>(&As[(mi << 4) + lr][(kk << 5) + (lk << 3)]);
                acc[mi] = __builtin_amdgcn_mfma_f32_16x16x32_bf16(a, bb, acc[mi], 0, 0, 0);
            }
        }
        __syncthreads();
    }
    int n = n0 + (w << 4) + lr;
    int gate = n >> 10, jj = n & 1023;
    float bias = bih[n] + (gate < 2 ? bhh[n] : 0.0f);
    #pragma unroll
    for (int mi = 0; mi < 4; ++mi)
        #pragma unroll
        for (int reg = 0; reg < 4; ++reg) {
            int m = m0 + (mi << 4) + (lk << 2) + reg;
            Gp[((((size_t)m << 10) | jj) << 2) + gate] = f2bf(acc[mi][reg] + bias);
        }
}

// ---------------- persistent recurrence: R8-verbatim (best measured, 4.25 ms) ----------------
__global__ __launch_bounds__(256, 1) void recur_kernel(
    const ushort* __restrict__ Whh_fr,
    const ushort* __restrict__ Gp,
    const int*    __restrict__ idxT,
    const float*  __restrict__ bhh,
    ushort* h_hist,      // [513][64][1024], slot 512 zeroed
    uint*   flags)
{
    extern __shared__ ushort dynlds[];          // [4][32][64][8] = 128 KB
    const int tid = threadIdx.x, blk = blockIdx.x;
    const int w = tid >> 6, l = tid & 63;
    const int lr = l & 15, lk = l >> 4;
    const int j0 = blk << 4, j = j0 + lr;
    const int b_base = (w << 4) + (lk << 2);
    const float bhhn = bhh[2048 + j];
    const ushort* Bbase = Whh_fr + (size_t)blk * 49152;   // 3*32*64*8
    ushort* myfrag = dynlds + (w << 14);                  // w*32*512
    const int rowoff = (((w << 4) + lr) << 10) + (lk << 3);
    float hfp[4] = {0.f, 0.f, 0.f, 0.f};
    bool dead = false;

    for (int t = 0; t < T_; ++t) {
        const ushort* src = h_hist + ((size_t)(t == 0 ? 512 : t - 1) << 16) + rowoff;
        #pragma unroll
        for (int c = 0; c < 32; ++c)
            gll16(src + (c << 5), myfrag + (c << 9));
        __syncthreads();   // drains gll vmcnt

        f32x4 acc0 = {0.f,0.f,0.f,0.f}, acc1 = acc0, acc2 = acc0;
        #pragma unroll
        for (int c = 0; c < 32; ++c) {
            bf16x8 a = *reinterpret_cast<const bf16x8*>(myfrag + (c << 9) + (l << 3));
            bf16x8 b0 = *reinterpret_cast<const bf16x8*>(Bbase +         (c << 9) + (l << 3));
            bf16x8 b1 = *reinterpret_cast<const bf16x8*>(Bbase + 16384 + (c << 9) + (l << 3));
            bf16x8 b2 = *reinterpret_cast<const bf16x8*>(Bbase + 32768 + (c << 9) + (l << 3));
            acc0 = __builtin_amdgcn_mfma_f32_16x16x32_bf16(a, b0, acc0, 0, 0, 0);
            acc1 = __builtin_amdgcn_mfma_f32_16x16x32_bf16(a, b1, acc1, 0, 0, 0);
            acc2 = __builtin_amdgcn_mfma_f32_16x16x32_bf16(a, b2, acc2, 0, 0, 0);
        }

        ushort* hw = h_hist + ((size_t)t << 16);
        const uint4 it4 = *reinterpret_cast<const uint4*>(idxT + (t << 6) + b_base);
        const int* itp = (const int*)&it4;
        #pragma unroll
        for (int reg = 0; reg < 4; ++reg) {
            const int b = b_base + reg;
            const ushort4 g4 = *reinterpret_cast<const ushort4*>(Gp + ((((size_t)itp[reg] << 10) | j) << 2));
            float rr = sigf(bf2f(g4.x) + acc0[reg]);
            float zz = sigf(bf2f(g4.y) + acc1[reg]);
            float nn = tanhfast(bf2f(g4.z) + rr * (acc2[reg] + bhhn));
            float hn = (1.0f - zz) * nn + zz * hfp[reg];
            hfp[reg] = hn;
            astore(&hw[(b << 10) + j], f2bf(hn));
        }

        if (t < T_ - 1) {
            __syncthreads();   // compiler emits vmcnt(0) drain before s_barrier -> h stores landed
            if (tid == 0)
                __hip_atomic_store(&flags[blk << 4], (uint)(t + 1),
                                   __ATOMIC_RELAXED, __HIP_MEMORY_SCOPE_AGENT);
            if (!dead) {       // all 256 threads busy-poll (fast detect + keeps clocks up)
                uint spins = 0;
                while (__hip_atomic_load(&flags[(tid & 63) << 4], __ATOMIC_RELAXED,
                                         __HIP_MEMORY_SCOPE_AGENT) < (uint)(t + 1)) {
                    if (++spins > (1u << 20)) { dead = true; break; }  // bounded: no hang
                }
            }
            __syncthreads();
        }
    }
}

// ---------------- fused tail: proj + CPC, one block per t ----------------
// LDS: h frags [c32][mi4][lane64][8] = 128 KB  |  hp tile [64][72] ushort = 9 KB
__global__ __launch_bounds__(256, 1) void tail_kernel(
    const ushort* __restrict__ h_hist,
    const ushort* __restrict__ pW_fr,
    const float*  __restrict__ projb,
    const float*  __restrict__ Z,
    double* __restrict__ cp_sum)
{
    extern __shared__ ushort dynlds[];
    ushort* hp = dynlds + 65536;                 // byte offset 131072
    const int t = blockIdx.x;
    const int tid = threadIdx.x;
    const int w = tid >> 6, l = tid & 63;
    const int lr = l & 15, lk = l >> 4;

    // stage h_hist[t] into shared fragment layout (all 4 waves cooperate)
    const ushort* hsrc = h_hist + ((size_t)t << 16);
    #pragma unroll
    for (int i = 0; i < 32; ++i) {
        int u = (w << 5) + i;                    // unit = c*4 + mi
        int c = u >> 2, mi = u & 3;
        const ushort* s = hsrc + ((size_t)((mi << 4) + lr) << 10) + (c << 5) + (lk << 3);
        gll16(s, dynlds + (u << 9));
    }
    __syncthreads();                             // drain + cross-wave share

    const int kfmax = (t < T_ - 3) ? 3 : (t < T_ - 2 ? 2 : (t < T_ - 1 ? 1 : 0));
    f32x4 accg[3][4];
    #pragma unroll
    for (int a = 0; a < 3; ++a)
        #pragma unroll
        for (int b = 0; b < 4; ++b) accg[a][b] = f32x4{0.f,0.f,0.f,0.f};

    for (int nt = 0; nt < 16; ++nt) {
        // ---- phase 1: hproj tile = h @ projW^T (n = nt*64 + w*16 + lr) ----
        f32x4 accp[4];
        #pragma unroll
        for (int i = 0; i < 4; ++i) accp[i] = f32x4{0.f,0.f,0.f,0.f};
        const ushort* pwb = pW_fr + ((size_t)((nt << 2) + w) << 14);   // ng*32 units *512
        for (int c = 0; c < 32; ++c) {
            bf16x8 bfr = *reinterpret_cast<const bf16x8*>(pwb + (c << 9) + (l << 3));
            #pragma unroll
            for (int mi = 0; mi < 4; ++mi) {
                bf16x8 afr = *reinterpret_cast<const bf16x8*>(dynlds + (((c << 2) + mi) << 9) + (l << 3));
                accp[mi] = __builtin_amdgcn_mfma_f32_16x16x32_bf16(afr, bfr, accp[mi], 0, 0, 0);
            }
        }
        float pb = projb[(nt << 6) + (w << 4) + lr];
        #pragma unroll
        for (int mi = 0; mi < 4; ++mi)
            #pragma unroll
            for (int reg = 0; reg < 4; ++reg) {
                int b = (mi << 4) + (lk << 2) + reg;     // D row = 4*lk+reg within sub
                hp[b * 72 + (w << 4) + lr] = f2bf(accp[mi][reg] + pb);
            }
        __syncthreads();                         // hp tile visible to all waves

        // ---- phase 2: Gram partial over this 64-d slice, 3 future offsets ----
        for (int kf = 1; kf <= kfmax; ++kf) {
            const float* zr = Z + ((((size_t)((w << 4) + lr) << 9) + (t + kf)) << 10) + (nt << 6);
            #pragma unroll
            for (int ck2 = 0; ck2 < 2; ++ck2) {
                const float* zc = zr + (ck2 << 5) + (lk << 3);
                float4 z0 = *reinterpret_cast<const float4*>(zc);
                float4 z1 = *reinterpret_cast<const float4*>(zc + 4);
                uint4 pk;
                pk.x = (uint)f2bf(z0.x) | ((uint)f2bf(z0.y) << 16);
                pk.y = (uint)f2bf(z0.z) | ((uint)f2bf(z0.w) << 16);
                pk.z = (uint)f2bf(z1.x) | ((uint)f2bf(z1.y) << 16);
                pk.w = (uint)f2bf(z1.z) | ((uint)f2bf(z1.w) << 16);
                bf16x8 zfr = *reinterpret_cast<bf16x8*>(&pk);
                #pragma unroll
                for (int mi2 = 0; mi2 < 4; ++mi2) {
                    bf16x8 afr = *reinterpret_cast<const bf16x8*>(
                        hp + ((mi2 << 4) + lr) * 72 + (ck2 << 5) + (lk << 3));
                    accg[kf - 1][mi2] = __builtin_amdgcn_mfma_f32_16x16x32_bf16(
                        afr, zfr, accg[kf - 1][mi2], 0, 0, 0);
                }
            }
        }
        __syncthreads();                         // hp reads done before next overwrite
    }

    // ---- loss: thread holds Gram[b][c], b = mi2*16 + 4*lk + reg, c = 16w + lr ----
    double lsum = 0.0;
    const int c = (w << 4) + lr;
    for (int kf = 1; kf <= kfmax; ++kf) {
        #pragma unroll
        for (int mi2 = 0; mi2 < 4; ++mi2)
            #pragma unroll
            for (int reg = 0; reg < 4; ++reg) {
                int b = (mi2 << 4) + (lk << 2) + reg;
                double v = (double)accg[kf - 1][mi2][reg];
                double sg = 1.0 / (1.0 + exp(-v));
                lsum += (0.1 / 4096.0) * (-log(1.0 - sg + 1e-8));
                if (b == c) lsum += (1.0 / 64.0) * (-log(sg + 1e-8));
            }
    }
    __syncthreads();                             // before reusing dynlds as reduction buf
    double* red = (double*)dynlds;
    red[tid] = lsum; __syncthreads();
    for (int s2 = 128; s2 > 0; s2 >>= 1) {
        if (tid < s2) red[tid] += red[tid + s2];
        __syncthreads();
    }
    if (tid == 0 && kfmax > 0) atomicAdd(cp_sum, red[0]);
}

// ---------------- finalize ----------------
__global__ void finalize_kernel(const double* __restrict__ accum,
                                float* __restrict__ scal) {
    double cp = accum[0] / 1527.0;
    double vq = accum[1] * 1.25 / (double)NQ_;
    scal[0] = (float)(cp + vq);
    scal[1] = (float)cp;
    scal[2] = (float)vq;
}

extern "C" void kernel_launch(void* const* d_in, const int* in_sizes, int n_in,
                              void* d_out, int out_size, void* d_ws, size_t ws_size,
                              hipStream_t stream) {
    const float* Z     = (const float*)d_in[0];
    const float* cb    = (const float*)d_in[1];
    const float* Wih   = (const float*)d_in[2];
    const float* Whh   = (const float*)d_in[3];
    const float* bih   = (const float*)d_in[4];
    const float* bhh   = (const float*)d_in[5];
    const float* projW = (const float*)d_in[6];
    const float* projb = (const float*)d_in[7];

    float* out       = (float*)d_out;
    float* quantized = out;
    float* idxout    = out + (size_t)NQ_;
    float* scal      = out + (size_t)NQ_ + NI_;

    char* p = (char*)d_ws;
    ushort* Whh_fr = (ushort*)p;  p += 6291456;
    ushort* pW_fr  = (ushort*)p;  p += 2097152;
    ushort* Gp     = (ushort*)p;  p += 2097152;
    int*    idxT   = (int*)p;     p += 131072;
    float*  c2f    = (float*)p;   p += 4096;
    char*   ctrl   = p;           p += 8192;    // 4KB flags (64 x 64B) + accum
    ushort* h_hist = (ushort*)p;  p += (size_t)513 * 131072;   // 67.24 MB -> total ~74 MB

    uint*   flags = (uint*)ctrl;
    double* accum = (double*)(ctrl + 4096);

    hipMemsetAsync(ctrl, 0, 8192, stream);
    hipMemsetAsync(h_hist + ((size_t)512 << 16), 0, 131072, stream);  // zero h0 slot

    whhfr_kernel<<<1536, 256, 0, stream>>>(Whh, Whh_fr);
    pwfr_kernel<<<512, 256, 0, stream>>>(projW, pW_fr);
    c2_kernel<<<1, 256, 0, stream>>>(cb, c2f);
    quantize_kernel<<<4096, 256, 0, stream>>>(Z, cb, c2f, quantized, idxout, idxT,
                                              &accum[1]);
    gmat_kernel<<<dim3(4, 48), 256, 0, stream>>>(cb, Wih, bih, bhh, Gp);

    // 64 blocks x 256 threads, 128 KB dyn LDS -> 1 block/CU, co-resident on 64 of 256 CUs
    hipFuncSetAttribute(reinterpret_cast<const void*>(recur_kernel),
                        hipFuncAttributeMaxDynamicSharedMemorySize, 131072);
    recur_kernel<<<dim3(64), dim3(256), 131072, stream>>>(Whh_fr, Gp, idxT, bhh,
                                                          h_hist, flags);

    // fused proj+CPC: 512 blocks (one per t), 140 KB dyn LDS
    hipFuncSetAttribute(reinterpret_cast<const void*>(tail_kernel),
                        hipFuncAttributeMaxDynamicSharedMemorySize, 140288);
    tail_kernel<<<dim3(512), dim3(256), 140288, stream>>>(h_hist, pW_fr, projb, Z,
                                                          &accum[0]);

    finalize_kernel<<<1, 1, 0, stream>>>(accum, scal);
}